// Round 1
// baseline (19050.351 us; speedup 1.0000x reference)
//
#include <hip/hip_runtime.h>
#include <math.h>

#define NN_ 128   // batch
#define TT  100   // time steps
#define SS  128   // state dim
#define AA  32    // action dim
#define LL  1024  // hidden (= Z)

__device__ __forceinline__ float sigmoidf_(float x) { return 1.0f / (1.0f + expf(-x)); }

// ---------------------------------------------------------------- init
__global__ void init_kernel(float* loss, int* maxlim) {
    if (threadIdx.x == 0) { loss[0] = 0.0f; maxlim[0] = 0; }
}

// ---------------------------------------------------------------- split points + h0(enc)=ones
// end[n] = lengths[n]-1 ; start[n] = lengths[n]+1 ; limit[n] = 99 - lengths[n]
__global__ void split_kernel(const float* __restrict__ s, int* __restrict__ endv,
                             int* __restrict__ startv, int* __restrict__ limitv,
                             int* __restrict__ maxlim, float* __restrict__ h_enc0) {
    const int n = blockIdx.x, tid = threadIdx.x;
    __shared__ int mint;
    if (tid == 0) mint = TT - 1;
    __syncthreads();
    int t = tid + 1;
    if (t < TT) {
        const float* row = s + (size_t)n * TT * SS + (size_t)t * SS;
        bool allz = true;
        for (int i = 0; i < SS; ++i) { if (row[i] != 0.0f) { allz = false; break; } }
        if (allz) atomicMin(&mint, t);
    }
    __syncthreads();
    if (tid == 0) {
        int m = mint;
        endv[n]   = m - 1;
        startv[n] = m + 1;
        int lim   = TT - 1 - m;
        limitv[n] = lim;
        atomicMax(maxlim, lim);
    }
    for (int idx = tid; idx < LL; idx += 128) h_enc0[(size_t)n * LL + idx] = 1.0f;
}

// ---------------------------------------------------------------- GRU step (+ fused decoder head/loss)
// matmul blocks [0,256): tile 32n x 16j, micro 1n x 2j, gates r/z/n (n-gate keeps x and h parts split)
// head blocks [256,384) (decoder only): MLP head + masked L1 loss for dec_out[t-1] = h_in
template<int XK, bool IS_DEC>
__global__ __launch_bounds__(256)
void gru_step(const float* __restrict__ h_in, float* __restrict__ h_out,
              const float* __restrict__ Whh, const float* __restrict__ Wih,
              const float* __restrict__ bih, const float* __restrict__ bhh,
              const float* __restrict__ xs, const float* __restrict__ xa,
              const int* __restrict__ endv, const int* __restrict__ startv,
              const int* __restrict__ limitv, const int* __restrict__ maxlim,
              float* __restrict__ hf,
              const float* __restrict__ d1W, const float* __restrict__ d1b,
              const float* __restrict__ d2W, const float* __restrict__ d2b,
              const float* __restrict__ d3W, const float* __restrict__ d3b,
              const float* __restrict__ s_next, float* __restrict__ loss,
              int t) {
    __shared__ __align__(16) float lds_h[64][33];      // [k][n]
    __shared__ __align__(16) float lds_w[3][64][18];   // [g][k][j]
    const int tid = threadIdx.x;

    if (blockIdx.x < 256) {
        if (IS_DEC && t >= maxlim[0]) return;           // steps past max useful limit
        const int jb = (blockIdx.x & 63) * 16;
        const int nb = (blockIdx.x >> 6) * 32;
        const int tn = tid & 31;
        const int tj = tid >> 5;                        // 0..7
        const int j0 = jb + tj * 2;
        const int n  = nb + tn;

        float ar0  = bih[j0]        + bhh[j0];
        float ar1  = bih[j0 + 1]    + bhh[j0 + 1];
        float az0  = bih[LL + j0]   + bhh[LL + j0];
        float az1  = bih[LL + j0+1] + bhh[LL + j0+1];
        float ahn0 = bhh[2*LL + j0],   ahn1 = bhh[2*LL + j0+1];   // hidden n-part (gets r*)
        float axn0 = bih[2*LL + j0],   axn1 = bih[2*LL + j0+1];   // input  n-part

        // ---- hidden contribution, K = 1024
        for (int kc = 0; kc < LL; kc += 64) {
            for (int idx = tid; idx < 32 * 64; idx += 256) {
                int k = idx & 63, nn = idx >> 6;
                lds_h[k][nn] = h_in[(size_t)(nb + nn) * LL + kc + k];
            }
            for (int idx = tid; idx < 3 * 16 * 64; idx += 256) {
                int k = idx & 63, j = (idx >> 6) & 15, g = idx >> 10;
                lds_w[g][k][j] = Whh[(size_t)(g * LL + jb + j) * LL + kc + k];
            }
            __syncthreads();
            #pragma unroll 4
            for (int k = 0; k < 64; ++k) {
                float hv = lds_h[k][tn];
                float2 wr = *(const float2*)&lds_w[0][k][tj * 2];
                float2 wz = *(const float2*)&lds_w[1][k][tj * 2];
                float2 wn = *(const float2*)&lds_w[2][k][tj * 2];
                ar0 += hv * wr.x; ar1 += hv * wr.y;
                az0 += hv * wz.x; az1 += hv * wz.y;
                ahn0 += hv * wn.x; ahn1 += hv * wn.y;
            }
            __syncthreads();
        }
        // ---- input contribution, K = XK (enc: s||a = 160, dec: rolled a = 32), chunks of 32
        for (int kc = 0; kc < XK; kc += 32) {
            for (int idx = tid; idx < 32 * 32; idx += 256) {
                int k = idx & 31, nn = idx >> 5;
                float v;
                if (IS_DEC) {
                    int tr = t + startv[nb + nn]; if (tr >= TT) tr -= TT;
                    v = xs[(size_t)(nb + nn) * TT * AA + (size_t)tr * AA + k];
                } else {
                    int i = kc + k;
                    v = (i < SS) ? xs[(size_t)(nb + nn) * TT * SS + (size_t)t * SS + i]
                                 : xa[(size_t)(nb + nn) * TT * AA + (size_t)t * AA + (i - SS)];
                }
                lds_h[k][nn] = v;
            }
            for (int idx = tid; idx < 3 * 16 * 32; idx += 256) {
                int k = idx & 31, j = (idx >> 5) & 15, g = idx >> 9;
                lds_w[g][k][j] = Wih[(size_t)(g * LL + jb + j) * XK + kc + k];
            }
            __syncthreads();
            #pragma unroll 4
            for (int k = 0; k < 32; ++k) {
                float hv = lds_h[k][tn];
                float2 wr = *(const float2*)&lds_w[0][k][tj * 2];
                float2 wz = *(const float2*)&lds_w[1][k][tj * 2];
                float2 wn = *(const float2*)&lds_w[2][k][tj * 2];
                ar0 += hv * wr.x; ar1 += hv * wr.y;
                az0 += hv * wz.x; az1 += hv * wz.y;
                axn0 += hv * wn.x; axn1 += hv * wn.y;
            }
            __syncthreads();
        }
        // ---- gate math + state update
        float2 hold = *(const float2*)&h_in[(size_t)n * LL + j0];
        float r0 = sigmoidf_(ar0), r1 = sigmoidf_(ar1);
        float z0 = sigmoidf_(az0), z1 = sigmoidf_(az1);
        float g0 = tanhf(axn0 + r0 * ahn0);
        float g1 = tanhf(axn1 + r1 * ahn1);
        float2 o = make_float2((1.0f - z0) * g0 + z0 * hold.x,
                               (1.0f - z1) * g1 + z1 * hold.y);
        *(float2*)&h_out[(size_t)n * LL + j0] = o;
        if (!IS_DEC) {
            if (endv[n] == t) *(float2*)&hf[(size_t)n * LL + j0] = o;
        }
    } else {
        // ---------------- decoder head + loss for dec_out[t-1] == h_in[n]
        if (!IS_DEC) return;
        const int n = blockIdx.x - 256;
        if (t == 0) return;
        const int ti = t - 1;
        if (ti >= limitv[n]) return;   // masked out for this sample
        __shared__ float sh[LL];
        __shared__ float y1s[128];
        __shared__ float y2s[64];
        for (int z = tid; z < LL; z += 256) sh[z] = h_in[(size_t)n * LL + z];
        __syncthreads();
        const int wid = tid >> 6, lane = tid & 63;
        for (int c = wid; c < 128; c += 4) {
            float acc = 0.0f;
            const float* wrow = d1W + (size_t)c * LL;
            for (int z = lane; z < LL; z += 64) acc += sh[z] * wrow[z];
            for (int off = 32; off >= 1; off >>= 1) acc += __shfl_down(acc, off);
            if (lane == 0) y1s[c] = fmaxf(acc + d1b[c], 0.0f);
        }
        __syncthreads();
        for (int c = wid; c < 64; c += 4) {
            float acc = 0.0f;
            const float* wrow = d2W + (size_t)c * 128;
            for (int z = lane; z < 128; z += 64) acc += y1s[z] * wrow[z];
            for (int off = 32; off >= 1; off >>= 1) acc += __shfl_down(acc, off);
            if (lane == 0) y2s[c] = fmaxf(acc + d2b[c], 0.0f);
        }
        __syncthreads();
        int tr = ti + startv[n]; if (tr >= TT) tr -= TT;
        const float* srow = s_next + (size_t)n * TT * SS + (size_t)tr * SS;
        float lsum = 0.0f;
        for (int c = wid; c < 128; c += 4) {
            float acc = y2s[lane] * d3W[(size_t)c * 64 + lane];   // lane in [0,64)
            for (int off = 32; off >= 1; off >>= 1) acc += __shfl_down(acc, off);
            if (lane == 0) lsum += fabsf(srow[c] - (acc + d3b[c]));
        }
        if (lane == 0) atomicAdd(loss, lsum);
    }
}

// ---------------------------------------------------------------- reparametrize: emb -> h_dec0
// mu = hf@muW.T + mub ; lv = hf@lvW.T + lvb ; emb = mu + exp(lv/2)*eps
__global__ __launch_bounds__(256)
void emb_kernel(const float* __restrict__ hf,
                const float* __restrict__ muW, const float* __restrict__ mub,
                const float* __restrict__ lvW, const float* __restrict__ lvb,
                const float* __restrict__ eps, float* __restrict__ h_dec0) {
    __shared__ __align__(16) float lds_h[64][33];
    __shared__ __align__(16) float lds_w[2][64][18];
    const int tid = threadIdx.x;
    const int jb = (blockIdx.x & 63) * 16;
    const int nb = (blockIdx.x >> 6) * 32;
    const int tn = tid & 31, tj = tid >> 5;
    const int j0 = jb + tj * 2, n = nb + tn;
    float am0 = 0, am1 = 0, al0 = 0, al1 = 0;
    for (int kc = 0; kc < LL; kc += 64) {
        for (int idx = tid; idx < 32 * 64; idx += 256) {
            int k = idx & 63, nn = idx >> 6;
            lds_h[k][nn] = hf[(size_t)(nb + nn) * LL + kc + k];
        }
        for (int idx = tid; idx < 2 * 16 * 64; idx += 256) {
            int k = idx & 63, j = (idx >> 6) & 15, g = idx >> 10;
            const float* W = g ? lvW : muW;
            lds_w[g][k][j] = W[(size_t)(jb + j) * LL + kc + k];
        }
        __syncthreads();
        #pragma unroll 4
        for (int k = 0; k < 64; ++k) {
            float hv = lds_h[k][tn];
            float2 wm = *(const float2*)&lds_w[0][k][tj * 2];
            float2 wl = *(const float2*)&lds_w[1][k][tj * 2];
            am0 += hv * wm.x; am1 += hv * wm.y;
            al0 += hv * wl.x; al1 += hv * wl.y;
        }
        __syncthreads();
    }
    float mu0 = am0 + mub[j0],     mu1 = am1 + mub[j0 + 1];
    float lv0 = al0 + lvb[j0],     lv1 = al1 + lvb[j0 + 1];
    float e0 = mu0 + expf(0.5f * lv0) * eps[(size_t)n * LL + j0];
    float e1 = mu1 + expf(0.5f * lv1) * eps[(size_t)n * LL + j0 + 1];
    *(float2*)&h_dec0[(size_t)n * LL + j0] = make_float2(e0, e1);
}

// ---------------------------------------------------------------- launch
extern "C" void kernel_launch(void* const* d_in, const int* in_sizes, int n_in,
                              void* d_out, int out_size, void* d_ws, size_t ws_size,
                              hipStream_t stream) {
    const float* s      = (const float*)d_in[0];
    const float* a      = (const float*)d_in[1];
    const float* s_next = (const float*)d_in[3];
    const float* eps    = (const float*)d_in[4];
    const float* eWih   = (const float*)d_in[5];
    const float* eWhh   = (const float*)d_in[6];
    const float* ebih   = (const float*)d_in[7];
    const float* ebhh   = (const float*)d_in[8];
    const float* muW    = (const float*)d_in[9];
    const float* mub    = (const float*)d_in[10];
    const float* lvW    = (const float*)d_in[11];
    const float* lvb    = (const float*)d_in[12];
    // st1..st3 (indices 13..18) are dead code w.r.t. the returned loss
    const float* dWih   = (const float*)d_in[19];
    const float* dWhh   = (const float*)d_in[20];
    const float* dbih   = (const float*)d_in[21];
    const float* dbhh   = (const float*)d_in[22];
    const float* d1W    = (const float*)d_in[23];
    const float* d1b    = (const float*)d_in[24];
    const float* d2W    = (const float*)d_in[25];
    const float* d2b    = (const float*)d_in[26];
    const float* d3W    = (const float*)d_in[27];
    const float* d3b    = (const float*)d_in[28];
    float* loss = (float*)d_out;

    char* ws   = (char*)d_ws;
    int* maxlim = (int*)ws;
    int* endv   = (int*)(ws + 256);
    int* startv = (int*)(ws + 256 + 512);
    int* limitv = (int*)(ws + 256 + 1024);
    float* hencA = (float*)(ws + 4096);
    float* hencB = hencA + (size_t)NN_ * LL;
    float* hfb   = hencB + (size_t)NN_ * LL;
    float* hdecA = hfb   + (size_t)NN_ * LL;
    float* hdecB = hdecA + (size_t)NN_ * LL;

    hipLaunchKernelGGL(init_kernel, dim3(1), dim3(64), 0, stream, loss, maxlim);
    hipLaunchKernelGGL(split_kernel, dim3(128), dim3(128), 0, stream,
                       s, endv, startv, limitv, maxlim, hencA);

    // encoder: end[n] <= 97, so 98 steps suffice
    for (int t = 0; t < 98; ++t) {
        const float* hin = (t & 1) ? hencB : hencA;
        float*       hout = (t & 1) ? hencA : hencB;
        hipLaunchKernelGGL((gru_step<160, false>), dim3(256), dim3(256), 0, stream,
                           hin, hout, eWhh, eWih, ebih, ebhh, s, a,
                           endv, startv, limitv, maxlim, hfb,
                           (const float*)nullptr, (const float*)nullptr,
                           (const float*)nullptr, (const float*)nullptr,
                           (const float*)nullptr, (const float*)nullptr,
                           (const float*)nullptr, loss, t);
    }

    hipLaunchKernelGGL(emb_kernel, dim3(256), dim3(256), 0, stream,
                       hfb, muW, mub, lvW, lvb, eps, hdecA);

    // decoder: limit[n] = 99 - lengths[n] <= 49, so 50 launches cover all
    // contributing steps; launch i fuses head/loss for dec_out[i-1].
    for (int i = 0; i < 50; ++i) {
        const float* hin = (i & 1) ? hdecB : hdecA;
        float*       hout = (i & 1) ? hdecA : hdecB;
        hipLaunchKernelGGL((gru_step<32, true>), dim3(384), dim3(256), 0, stream,
                           hin, hout, dWhh, dWih, dbih, dbhh, a, (const float*)nullptr,
                           endv, startv, limitv, maxlim, (float*)nullptr,
                           d1W, d1b, d2W, d2b, d3W, d3b, s_next, loss, i);
    }
}

// Round 2
// 5717.608 us; speedup vs baseline: 3.3319x; 3.3319x over previous
//
#include <hip/hip_runtime.h>
#include <math.h>

#define NN_ 128   // batch
#define TT  100   // time steps
#define SS  128   // state dim
#define AA  32    // action dim
#define LL  1024  // hidden (= Z)

typedef __attribute__((ext_vector_type(8))) short bf16x8;   // 8 bf16 in 4 VGPRs
typedef __attribute__((ext_vector_type(4))) float f32x4;

__device__ __forceinline__ float sigmoidf_(float x) { return 1.0f / (1.0f + expf(-x)); }
__device__ __forceinline__ unsigned short f2bf(float x) {
    union { float f; unsigned u; } v; v.f = x;
    unsigned r = (v.u + 0x7fffu + ((v.u >> 16) & 1u)) >> 16;   // RNE
    return (unsigned short)r;
}

// ---------------------------------------------------------------- init
__global__ void init_kernel(float* loss, int* maxlim) {
    if (threadIdx.x == 0) { loss[0] = 0.0f; maxlim[0] = 0; }
}

// ---------------------------------------------------------------- split points, h0(enc)=ones (fp32+bf16), rolled dec actions (bf16)
__global__ void split_kernel(const float* __restrict__ s, const float* __restrict__ a,
                             int* __restrict__ endv, int* __restrict__ startv,
                             int* __restrict__ limitv, int* __restrict__ maxlim,
                             float* __restrict__ h0f, unsigned short* __restrict__ h0b,
                             unsigned short* __restrict__ adec) {
    const int n = blockIdx.x, tid = threadIdx.x;
    __shared__ int mint;
    if (tid == 0) mint = TT - 1;
    __syncthreads();
    int t = tid + 1;
    if (t < TT) {
        const float* row = s + (size_t)n * TT * SS + (size_t)t * SS;
        bool allz = true;
        for (int i = 0; i < SS; ++i) { if (row[i] != 0.0f) { allz = false; break; } }
        if (allz) atomicMin(&mint, t);
    }
    __syncthreads();
    const int m = mint;
    const int st = m + 1;
    if (tid == 0) {
        endv[n] = m - 1; startv[n] = st;
        int lim = TT - 1 - m;
        limitv[n] = lim;
        atomicMax(maxlim, lim);
    }
    for (int idx = tid; idx < LL; idx += 128) {
        h0f[(size_t)n * LL + idx] = 1.0f;
        h0b[(size_t)n * LL + idx] = 0x3F80;
    }
    // rolled decoder actions, 50 steps suffice (limit <= 49)
    for (int idx = tid; idx < 50 * AA; idx += 128) {
        int i = idx >> 5, k = idx & 31;
        int tr = i + st; if (tr >= TT) tr -= TT;
        adec[(size_t)n * (50 * AA) + idx] = f2bf(a[(size_t)n * TT * AA + (size_t)tr * AA + k]);
    }
}

// ---------------------------------------------------------------- cast weights + concat enc input to bf16
__global__ void cast_kernel(const float* __restrict__ eWih, const float* __restrict__ eWhh,
                            const float* __restrict__ dWih, const float* __restrict__ dWhh,
                            const float* __restrict__ muW, const float* __restrict__ lvW,
                            const float* __restrict__ s, const float* __restrict__ a,
                            unsigned short* eWih_b, unsigned short* eWhh_b,
                            unsigned short* dWih_b, unsigned short* dWhh_b,
                            unsigned short* mlW_b, unsigned short* xenc_b) {
    const long N0 = 3072L * 160, N1 = N0 + 3072L * 1024, N2 = N1 + 3072L * 32,
               N3 = N2 + 3072L * 1024, N4 = N3 + 1024L * 1024, N5 = N4 + 1024L * 1024,
               N6 = N5 + 128L * 100 * 160;
    for (long i = (long)blockIdx.x * blockDim.x + threadIdx.x; i < N6;
         i += (long)gridDim.x * blockDim.x) {
        if (i < N0)      eWih_b[i]            = f2bf(eWih[i]);
        else if (i < N1) eWhh_b[i - N0]       = f2bf(eWhh[i - N0]);
        else if (i < N2) dWih_b[i - N1]       = f2bf(dWih[i - N1]);
        else if (i < N3) dWhh_b[i - N2]       = f2bf(dWhh[i - N2]);
        else if (i < N4) mlW_b[i - N3]        = f2bf(muW[i - N3]);
        else if (i < N5) mlW_b[1024L*1024 + (i - N4)] = f2bf(lvW[i - N4]);
        else {
            long j = i - N5;                  // n*16000 + t*160 + k
            int  k = (int)(j % 160);
            long nt = j / 160;
            int  t = (int)(nt % 100), n = (int)(nt / 100);
            float v = (k < SS) ? s[(size_t)n * TT * SS + (size_t)t * SS + k]
                               : a[(size_t)n * TT * AA + (size_t)t * AA + (k - SS)];
            xenc_b[j] = f2bf(v);
        }
    }
}

// ---------------------------------------------------------------- MFMA GRU step (+ fused decoder head/loss)
// matmul blocks [0,256): 8 n-blocks x 32 j-blocks(32 wide); 4 waves = 2 j-tiles x 2 K-halves.
// Each wave: same j-range for gates r/z/n (hidden part) + separate x-part n-gate accumulator.
// head blocks [256,384) (decoder only): MLP head + masked L1 loss on dec_out[t-1] = h_in.
template<int XK, bool IS_DEC>
__global__ __launch_bounds__(256)
void gru_step(const unsigned short* __restrict__ h_bf, const float* __restrict__ h_fp,
              float* __restrict__ ho_fp, unsigned short* __restrict__ ho_bf,
              const unsigned short* __restrict__ Whh_b, const unsigned short* __restrict__ Wih_b,
              const unsigned short* __restrict__ x_bf,
              const float* __restrict__ bih, const float* __restrict__ bhh,
              const int* __restrict__ endv, const int* __restrict__ startv,
              const int* __restrict__ limitv, const int* __restrict__ maxlim,
              unsigned short* __restrict__ hf_bf,
              const float* __restrict__ d1W, const float* __restrict__ d1b,
              const float* __restrict__ d2W, const float* __restrict__ d2b,
              const float* __restrict__ d3W, const float* __restrict__ d3b,
              const float* __restrict__ s_next, float* __restrict__ loss, int t) {
    if (blockIdx.x < 256) {
        if (IS_DEC && t >= maxlim[0]) return;   // no step beyond max useful limit
        __shared__ f32x4 red[2][4][64];
        const int tid = threadIdx.x, lane = tid & 63, w = tid >> 6;
        const int jt = w & 1, kh = w >> 1;
        const int m = lane & 15, quad = lane >> 4;
        const int nb = (blockIdx.x >> 5) << 4;            // 0..112 step 16
        const int jb = (blockIdx.x & 31) * 32 + jt * 16;  // 0..1008 step 16
        const int jcol = jb + m;                          // B row / output col this lane serves

        f32x4 accr{}, accz{}, acchn{}, accxn{};

        // ---- hidden part: K = 1024, 32 chunks, split 16/16 across kh
        {
            const unsigned short* ap  = h_bf + (size_t)(nb + m) * LL + quad * 8;
            const unsigned short* brp = Whh_b + (size_t)(0 * LL + jcol) * LL + quad * 8;
            const unsigned short* bzp = Whh_b + (size_t)(1 * LL + jcol) * LL + quad * 8;
            const unsigned short* bnp = Whh_b + (size_t)(2 * LL + jcol) * LL + quad * 8;
            #pragma unroll 4
            for (int c = kh * 16; c < kh * 16 + 16; ++c) {
                const int k0 = c * 32;
                bf16x8 av = *(const bf16x8*)(ap + k0);
                bf16x8 br = *(const bf16x8*)(brp + k0);
                bf16x8 bz = *(const bf16x8*)(bzp + k0);
                bf16x8 bn = *(const bf16x8*)(bnp + k0);
                accr  = __builtin_amdgcn_mfma_f32_16x16x32_bf16(av, br, accr, 0, 0, 0);
                accz  = __builtin_amdgcn_mfma_f32_16x16x32_bf16(av, bz, accz, 0, 0, 0);
                acchn = __builtin_amdgcn_mfma_f32_16x16x32_bf16(av, bn, acchn, 0, 0, 0);
            }
        }
        // ---- input part: K = XK (enc 160, dec 32), chunks split across kh
        {
            const int XC = XK / 32, XC0 = (XC + 1) / 2;
            const size_t xstride = IS_DEC ? (size_t)(50 * AA) : (size_t)(TT * (SS + AA));
            const unsigned short* xp  = x_bf + (size_t)(nb + m) * xstride + (size_t)t * XK + quad * 8;
            const unsigned short* brp = Wih_b + (size_t)(0 * LL + jcol) * XK + quad * 8;
            const unsigned short* bzp = Wih_b + (size_t)(1 * LL + jcol) * XK + quad * 8;
            const unsigned short* bnp = Wih_b + (size_t)(2 * LL + jcol) * XK + quad * 8;
            #pragma unroll
            for (int c = (kh ? XC0 : 0); c < (kh ? XC : XC0); ++c) {
                const int k0 = c * 32;
                bf16x8 av = *(const bf16x8*)(xp + k0);
                bf16x8 br = *(const bf16x8*)(brp + k0);
                bf16x8 bz = *(const bf16x8*)(bzp + k0);
                bf16x8 bn = *(const bf16x8*)(bnp + k0);
                accr  = __builtin_amdgcn_mfma_f32_16x16x32_bf16(av, br, accr, 0, 0, 0);
                accz  = __builtin_amdgcn_mfma_f32_16x16x32_bf16(av, bz, accz, 0, 0, 0);
                accxn = __builtin_amdgcn_mfma_f32_16x16x32_bf16(av, bn, accxn, 0, 0, 0);
            }
        }
        // ---- split-K reduce + epilogue
        if (kh == 1) {
            red[jt][0][lane] = accr;  red[jt][1][lane] = accz;
            red[jt][2][lane] = acchn; red[jt][3][lane] = accxn;
        }
        __syncthreads();
        if (kh == 0) {
            accr  += red[jt][0][lane];  accz  += red[jt][1][lane];
            acchn += red[jt][2][lane];  accxn += red[jt][3][lane];
            const float br_  = bih[jcol] + bhh[jcol];
            const float bz_  = bih[LL + jcol] + bhh[LL + jcol];
            const float bxn_ = bih[2 * LL + jcol];
            const float bhn_ = bhh[2 * LL + jcol];
            #pragma unroll
            for (int i = 0; i < 4; ++i) {
                const int n = nb + quad * 4 + i;     // C layout: row = quad*4+reg, col = lane&15
                float r = sigmoidf_(accr[i] + br_);
                float z = sigmoidf_(accz[i] + bz_);
                float g = tanhf(accxn[i] + bxn_ + r * (acchn[i] + bhn_));
                float hold = h_fp[(size_t)n * LL + jcol];
                float hn = (1.0f - z) * g + z * hold;
                ho_fp[(size_t)n * LL + jcol] = hn;
                ho_bf[(size_t)n * LL + jcol] = f2bf(hn);
                if (!IS_DEC) { if (endv[n] == t) hf_bf[(size_t)n * LL + jcol] = f2bf(hn); }
            }
        }
    } else {
        // ---------------- decoder head + loss for dec_out[t-1] == h_in[n]
        if (!IS_DEC) return;
        const int tid = threadIdx.x;
        const int n = blockIdx.x - 256;
        if (t == 0) return;
        const int ti = t - 1;
        if (ti >= limitv[n]) return;
        __shared__ float sh[LL];
        __shared__ float y1s[128];
        __shared__ float y2s[64];
        for (int z = tid; z < LL; z += 256) sh[z] = h_fp[(size_t)n * LL + z];
        __syncthreads();
        const int wid = tid >> 6, lane = tid & 63;
        for (int c = wid; c < 128; c += 4) {
            float acc = 0.0f;
            const float* wrow = d1W + (size_t)c * LL;
            for (int z = lane; z < LL; z += 64) acc += sh[z] * wrow[z];
            for (int off = 32; off >= 1; off >>= 1) acc += __shfl_down(acc, off);
            if (lane == 0) y1s[c] = fmaxf(acc + d1b[c], 0.0f);
        }
        __syncthreads();
        for (int c = wid; c < 64; c += 4) {
            float acc = 0.0f;
            const float* wrow = d2W + (size_t)c * 128;
            for (int z = lane; z < 128; z += 64) acc += y1s[z] * wrow[z];
            for (int off = 32; off >= 1; off >>= 1) acc += __shfl_down(acc, off);
            if (lane == 0) y2s[c] = fmaxf(acc + d2b[c], 0.0f);
        }
        __syncthreads();
        int tr = ti + startv[n]; if (tr >= TT) tr -= TT;
        const float* srow = s_next + (size_t)n * TT * SS + (size_t)tr * SS;
        float lsum = 0.0f;
        for (int c = wid; c < 128; c += 4) {
            float acc = y2s[lane] * d3W[(size_t)c * 64 + lane];
            for (int off = 32; off >= 1; off >>= 1) acc += __shfl_down(acc, off);
            if (lane == 0) lsum += fabsf(srow[c] - (acc + d3b[c]));
        }
        if (lane == 0) atomicAdd(loss, lsum);
    }
}

// ---------------------------------------------------------------- MFMA reparametrize: emb -> h_dec0 (fp32 + bf16)
__global__ __launch_bounds__(256)
void emb_mfma(const unsigned short* __restrict__ hf_bf, const unsigned short* __restrict__ mlW_b,
              const float* __restrict__ mub, const float* __restrict__ lvb,
              const float* __restrict__ eps,
              float* __restrict__ hd_fp, unsigned short* __restrict__ hd_bf) {
    __shared__ f32x4 red[2][2][64];
    const int tid = threadIdx.x, lane = tid & 63, w = tid >> 6;
    const int jt = w & 1, kh = w >> 1;
    const int m = lane & 15, quad = lane >> 4;
    const int nb = (blockIdx.x >> 5) << 4;
    const int jb = (blockIdx.x & 31) * 32 + jt * 16;
    const int jcol = jb + m;
    f32x4 accm{}, accl{};
    const unsigned short* ap  = hf_bf + (size_t)(nb + m) * LL + quad * 8;
    const unsigned short* bmp = mlW_b + (size_t)jcol * LL + quad * 8;
    const unsigned short* blp = mlW_b + (size_t)(LL + jcol) * LL + quad * 8;
    #pragma unroll 4
    for (int c = kh * 16; c < kh * 16 + 16; ++c) {
        const int k0 = c * 32;
        bf16x8 av = *(const bf16x8*)(ap + k0);
        bf16x8 bm = *(const bf16x8*)(bmp + k0);
        bf16x8 bl = *(const bf16x8*)(blp + k0);
        accm = __builtin_amdgcn_mfma_f32_16x16x32_bf16(av, bm, accm, 0, 0, 0);
        accl = __builtin_amdgcn_mfma_f32_16x16x32_bf16(av, bl, accl, 0, 0, 0);
    }
    if (kh == 1) { red[jt][0][lane] = accm; red[jt][1][lane] = accl; }
    __syncthreads();
    if (kh == 0) {
        accm += red[jt][0][lane]; accl += red[jt][1][lane];
        #pragma unroll
        for (int i = 0; i < 4; ++i) {
            const int n = nb + quad * 4 + i;
            float mu = accm[i] + mub[jcol];
            float lv = accl[i] + lvb[jcol];
            float e = mu + expf(0.5f * lv) * eps[(size_t)n * LL + jcol];
            hd_fp[(size_t)n * LL + jcol] = e;
            hd_bf[(size_t)n * LL + jcol] = f2bf(e);
        }
    }
}

// ---------------------------------------------------------------- launch
extern "C" void kernel_launch(void* const* d_in, const int* in_sizes, int n_in,
                              void* d_out, int out_size, void* d_ws, size_t ws_size,
                              hipStream_t stream) {
    const float* s      = (const float*)d_in[0];
    const float* a      = (const float*)d_in[1];
    const float* s_next = (const float*)d_in[3];
    const float* eps    = (const float*)d_in[4];
    const float* eWih   = (const float*)d_in[5];
    const float* eWhh   = (const float*)d_in[6];
    const float* ebih   = (const float*)d_in[7];
    const float* ebhh   = (const float*)d_in[8];
    const float* muW    = (const float*)d_in[9];
    const float* mub    = (const float*)d_in[10];
    const float* lvW    = (const float*)d_in[11];
    const float* lvb    = (const float*)d_in[12];
    // st1..st3 (13..18) dead code w.r.t. the loss
    const float* dWih   = (const float*)d_in[19];
    const float* dWhh   = (const float*)d_in[20];
    const float* dbih   = (const float*)d_in[21];
    const float* dbhh   = (const float*)d_in[22];
    const float* d1W    = (const float*)d_in[23];
    const float* d1b    = (const float*)d_in[24];
    const float* d2W    = (const float*)d_in[25];
    const float* d2b    = (const float*)d_in[26];
    const float* d3W    = (const float*)d_in[27];
    const float* d3b    = (const float*)d_in[28];
    float* loss = (float*)d_out;

    char* p = (char*)d_ws;
    int*   maxlim = (int*)p;                       p += 256;
    int*   endv   = (int*)p;                       p += 512;
    int*   startv = (int*)p;                       p += 512;
    int*   limitv = (int*)p;                       p += 512 + 2304;  // pad to 4096 total
    float* hencAf = (float*)p;                     p += 128 * 1024 * 4;
    float* hencBf = (float*)p;                     p += 128 * 1024 * 4;
    float* hdecAf = (float*)p;                     p += 128 * 1024 * 4;
    float* hdecBf = (float*)p;                     p += 128 * 1024 * 4;
    unsigned short* hencAb = (unsigned short*)p;   p += 128 * 1024 * 2;
    unsigned short* hencBb = (unsigned short*)p;   p += 128 * 1024 * 2;
    unsigned short* hdecAb = (unsigned short*)p;   p += 128 * 1024 * 2;
    unsigned short* hdecBb = (unsigned short*)p;   p += 128 * 1024 * 2;
    unsigned short* hf_bf  = (unsigned short*)p;   p += 128 * 1024 * 2;
    unsigned short* eWih_b = (unsigned short*)p;   p += 3072 * 160 * 2;
    unsigned short* eWhh_b = (unsigned short*)p;   p += 3072 * 1024 * 2;
    unsigned short* dWih_b = (unsigned short*)p;   p += 3072 * 32 * 2;
    unsigned short* dWhh_b = (unsigned short*)p;   p += 3072 * 1024 * 2;
    unsigned short* mlW_b  = (unsigned short*)p;   p += 2048 * 1024 * 2;
    unsigned short* xenc_b = (unsigned short*)p;   p += 128 * 100 * 160 * 2;
    unsigned short* adec_b = (unsigned short*)p;   p += 128 * 50 * 32 * 2;

    hipLaunchKernelGGL(init_kernel, dim3(1), dim3(64), 0, stream, loss, maxlim);
    hipLaunchKernelGGL(split_kernel, dim3(128), dim3(128), 0, stream,
                       s, a, endv, startv, limitv, maxlim, hencAf, hencAb, adec_b);
    hipLaunchKernelGGL(cast_kernel, dim3(1024), dim3(256), 0, stream,
                       eWih, eWhh, dWih, dWhh, muW, lvW, s, a,
                       eWih_b, eWhh_b, dWih_b, dWhh_b, mlW_b, xenc_b);

    // encoder: end[n] <= 97 -> 98 steps
    for (int t = 0; t < 98; ++t) {
        const unsigned short* hib = (t & 1) ? hencBb : hencAb;
        const float*          hif = (t & 1) ? hencBf : hencAf;
        float*          hof = (t & 1) ? hencAf : hencBf;
        unsigned short* hob = (t & 1) ? hencAb : hencBb;
        hipLaunchKernelGGL((gru_step<160, false>), dim3(256), dim3(256), 0, stream,
                           hib, hif, hof, hob, eWhh_b, eWih_b, xenc_b, ebih, ebhh,
                           endv, startv, limitv, maxlim, hf_bf,
                           (const float*)nullptr, (const float*)nullptr,
                           (const float*)nullptr, (const float*)nullptr,
                           (const float*)nullptr, (const float*)nullptr,
                           (const float*)nullptr, loss, t);
    }

    hipLaunchKernelGGL(emb_mfma, dim3(256), dim3(256), 0, stream,
                       hf_bf, mlW_b, mub, lvb, eps, hdecAf, hdecAb);

    // decoder: limit[n] <= 49 -> 50 launches; launch i fuses head/loss for dec_out[i-1]
    for (int i = 0; i < 50; ++i) {
        const unsigned short* hib = (i & 1) ? hdecBb : hdecAb;
        const float*          hif = (i & 1) ? hdecBf : hdecAf;
        float*          hof = (i & 1) ? hdecAf : hdecBf;
        unsigned short* hob = (i & 1) ? hdecAb : hdecBb;
        hipLaunchKernelGGL((gru_step<32, true>), dim3(384), dim3(256), 0, stream,
                           hib, hif, hof, hob, dWhh_b, dWih_b, adec_b, dbih, dbhh,
                           endv, startv, limitv, maxlim, (unsigned short*)nullptr,
                           d1W, d1b, d2W, d2b, d3W, d3b, s_next, loss, i);
    }
}

// Round 5
// 4381.966 us; speedup vs baseline: 4.3474x; 1.3048x over previous
//
#include <hip/hip_runtime.h>
#include <math.h>

#define NN_ 128   // batch
#define TT  100   // time steps
#define SS  128   // state dim
#define AA  32    // action dim
#define LL  1024  // hidden (= Z)
#define NBLK 264  // 256 matmul tiles + 8 head blocks

typedef __attribute__((ext_vector_type(8))) short bf16x8;   // 8 bf16 in 4 VGPRs
typedef __attribute__((ext_vector_type(4))) float f32x4;

__device__ __forceinline__ float sigmoidf_(float x) { return 1.0f / (1.0f + expf(-x)); }
__device__ __forceinline__ unsigned short f2bf(float x) {
    union { float f; unsigned u; } v; v.f = x;
    return (unsigned short)((v.u + 0x7fffu + ((v.u >> 16) & 1u)) >> 16);   // RNE
}

struct PParams {
    const float *s, *a, *s_next, *eps;
    const float *eWih, *eWhh, *ebih, *ebhh;
    const float *muW, *mub, *lvW, *lvb;
    const float *dWih, *dWhh, *dbih, *dbhh;
    const float *d1W, *d1b, *d2W, *d2b, *d3W, *d3b;
    int *bar;                       // barrier state
    int *endv, *startv, *limitv;
    float *hencAf, *hencBf, *hdecAf, *hdecBf;
    unsigned short *hencAb, *hencBb, *hdecAb, *hdecBb, *hf_bf;
    unsigned short *eWih_b, *eWhh_b, *dWih_b, *dWhh_b, *mlW_b, *xenc_b, *adec_b;
    unsigned short *d1Wb, *d2Wb, *d3Wb;
    float *loss;
};

// ---------------------------------------------------------------- grid barrier
// bar layout (ints): [g*16] g<8 group counters; [128] master; [132] broken; [144 + b*16] per-block flags.
// Monotone counters (never reset); generation `gen` starts at 1.
__device__ void gbar(int* bar, int bid, int tid, int gen) {
    __syncthreads();
    if (tid == 0) {
        if (__hip_atomic_load(bar + 132, __ATOMIC_RELAXED, __HIP_MEMORY_SCOPE_AGENT) == 0) {
            __threadfence();   // release: write back this XCD's L2 (prior stores visible device-wide)
            const int g = bid & 7;
            int pos = __hip_atomic_fetch_add(bar + g * 16, 1, __ATOMIC_RELAXED, __HIP_MEMORY_SCOPE_AGENT);
            if (pos + 1 == (NBLK / 8) * gen) {
                int mp = __hip_atomic_fetch_add(bar + 128, 1, __ATOMIC_RELAXED, __HIP_MEMORY_SCOPE_AGENT);
                if (mp + 1 == 8 * gen) {
                    __threadfence();
                    for (int b = 0; b < NBLK; ++b)
                        __hip_atomic_store(bar + 144 + b * 16, gen, __ATOMIC_RELAXED, __HIP_MEMORY_SCOPE_AGENT);
                }
            }
            int it = 0;
            while (__hip_atomic_load(bar + 144 + bid * 16, __ATOMIC_RELAXED, __HIP_MEMORY_SCOPE_AGENT) < gen) {
                __builtin_amdgcn_s_sleep(2);
                if (++it > 20000000) {   // ~1s safety valve: mark broken, stop waiting
                    __hip_atomic_store(bar + 132, 1, __ATOMIC_RELAXED, __HIP_MEMORY_SCOPE_AGENT);
                    break;
                }
            }
            __threadfence();   // acquire: invalidate stale lines before reading others' data
        }
    }
    __syncthreads();
}

// ---------------------------------------------------------------- init (separate launch, stream-ordered)
__global__ void init_kernel(int* bar, float* loss) {
    for (int i = threadIdx.x; i < 5120; i += 256) bar[i] = 0;
    if (threadIdx.x == 0) loss[0] = 0.0f;
}

// ---------------------------------------------------------------- GRU step matmul tile
// 256 tiles: 8 n-blocks x 32 j-blocks(32 wide); 4 waves = 2 j-tiles x 2 K-halves.
template<int XK, bool IS_DEC>
__device__ void gru_tile(const int bid, const int tid,
    const unsigned short* __restrict__ h_bf, const float* __restrict__ h_fp,
    float* __restrict__ ho_fp, unsigned short* __restrict__ ho_bf,
    const unsigned short* __restrict__ Whh_b, const unsigned short* __restrict__ Wih_b,
    const unsigned short* __restrict__ x_bf,
    const float* __restrict__ bih, const float* __restrict__ bhh,
    const int* __restrict__ endv, unsigned short* __restrict__ hf_bf,
    int t, f32x4 (&red)[2][4][64])
{
    const int lane = tid & 63, w = tid >> 6;
    const int jt = w & 1, kh = w >> 1;
    const int m = lane & 15, quad = lane >> 4;
    const int nb = (bid >> 5) << 4;            // 0..112 step 16
    const int jb = (bid & 31) * 32 + jt * 16;  // 0..1008 step 16
    const int jcol = jb + m;

    f32x4 accr{}, accz{}, acchn{}, accxn{};

    {   // hidden: K = 1024, 32 chunks, split 16/16 across kh
        const unsigned short* ap  = h_bf + (size_t)(nb + m) * LL + quad * 8;
        const unsigned short* brp = Whh_b + (size_t)(0 * LL + jcol) * LL + quad * 8;
        const unsigned short* bzp = Whh_b + (size_t)(1 * LL + jcol) * LL + quad * 8;
        const unsigned short* bnp = Whh_b + (size_t)(2 * LL + jcol) * LL + quad * 8;
        #pragma unroll 4
        for (int c = kh * 16; c < kh * 16 + 16; ++c) {
            const int k0 = c * 32;
            bf16x8 av = *(const bf16x8*)(ap + k0);
            bf16x8 br = *(const bf16x8*)(brp + k0);
            bf16x8 bz = *(const bf16x8*)(bzp + k0);
            bf16x8 bn = *(const bf16x8*)(bnp + k0);
            accr  = __builtin_amdgcn_mfma_f32_16x16x32_bf16(av, br, accr, 0, 0, 0);
            accz  = __builtin_amdgcn_mfma_f32_16x16x32_bf16(av, bz, accz, 0, 0, 0);
            acchn = __builtin_amdgcn_mfma_f32_16x16x32_bf16(av, bn, acchn, 0, 0, 0);
        }
    }
    {   // input: K = XK (enc 160, dec 32), chunks split across kh
        const int XC = XK / 32, XC0 = (XC + 1) / 2;
        const size_t xstride = IS_DEC ? (size_t)(50 * AA) : (size_t)(TT * (SS + AA));
        const unsigned short* xp  = x_bf + (size_t)(nb + m) * xstride + (size_t)t * XK + quad * 8;
        const unsigned short* brp = Wih_b + (size_t)(0 * LL + jcol) * XK + quad * 8;
        const unsigned short* bzp = Wih_b + (size_t)(1 * LL + jcol) * XK + quad * 8;
        const unsigned short* bnp = Wih_b + (size_t)(2 * LL + jcol) * XK + quad * 8;
        #pragma unroll
        for (int c = (kh ? XC0 : 0); c < (kh ? XC : XC0); ++c) {
            const int k0 = c * 32;
            bf16x8 av = *(const bf16x8*)(xp + k0);
            bf16x8 br = *(const bf16x8*)(brp + k0);
            bf16x8 bz = *(const bf16x8*)(bzp + k0);
            bf16x8 bn = *(const bf16x8*)(bnp + k0);
            accr  = __builtin_amdgcn_mfma_f32_16x16x32_bf16(av, br, accr, 0, 0, 0);
            accz  = __builtin_amdgcn_mfma_f32_16x16x32_bf16(av, bz, accz, 0, 0, 0);
            accxn = __builtin_amdgcn_mfma_f32_16x16x32_bf16(av, bn, accxn, 0, 0, 0);
        }
    }
    if (kh == 1) {
        red[jt][0][lane] = accr;  red[jt][1][lane] = accz;
        red[jt][2][lane] = acchn; red[jt][3][lane] = accxn;
    }
    __syncthreads();
    if (kh == 0) {
        accr  += red[jt][0][lane];  accz  += red[jt][1][lane];
        acchn += red[jt][2][lane];  accxn += red[jt][3][lane];
        const float br_  = bih[jcol] + bhh[jcol];
        const float bz_  = bih[LL + jcol] + bhh[LL + jcol];
        const float bxn_ = bih[2 * LL + jcol];
        const float bhn_ = bhh[2 * LL + jcol];
        #pragma unroll
        for (int i = 0; i < 4; ++i) {
            const int n = nb + quad * 4 + i;     // C layout: row = quad*4+reg, col = lane&15
            float r = sigmoidf_(accr[i] + br_);
            float z = sigmoidf_(accz[i] + bz_);
            float g = tanhf(accxn[i] + bxn_ + r * (acchn[i] + bhn_));
            float hold = h_fp[(size_t)n * LL + jcol];
            float hn = (1.0f - z) * g + z * hold;
            ho_fp[(size_t)n * LL + jcol] = hn;
            ho_bf[(size_t)n * LL + jcol] = f2bf(hn);
            if (!IS_DEC) { if (endv[n] == t) hf_bf[(size_t)n * LL + jcol] = f2bf(hn); }
        }
    }
}

// ---------------------------------------------------------------- reparametrize tile
__device__ void emb_tile(const PParams& P, const int bid, const int tid,
                         f32x4 (&red)[2][4][64])
{
    const int lane = tid & 63, w = tid >> 6;
    const int jt = w & 1, kh = w >> 1;
    const int m = lane & 15, quad = lane >> 4;
    const int nb = (bid >> 5) << 4;
    const int jb = (bid & 31) * 32 + jt * 16;
    const int jcol = jb + m;
    f32x4 accm{}, accl{};
    const unsigned short* ap  = P.hf_bf + (size_t)(nb + m) * LL + quad * 8;
    const unsigned short* bmp = P.mlW_b + (size_t)jcol * LL + quad * 8;
    const unsigned short* blp = P.mlW_b + (size_t)(LL + jcol) * LL + quad * 8;
    #pragma unroll 4
    for (int c = kh * 16; c < kh * 16 + 16; ++c) {
        const int k0 = c * 32;
        bf16x8 av = *(const bf16x8*)(ap + k0);
        bf16x8 bm = *(const bf16x8*)(bmp + k0);
        bf16x8 bl = *(const bf16x8*)(blp + k0);
        accm = __builtin_amdgcn_mfma_f32_16x16x32_bf16(av, bm, accm, 0, 0, 0);
        accl = __builtin_amdgcn_mfma_f32_16x16x32_bf16(av, bl, accl, 0, 0, 0);
    }
    if (kh == 1) { red[jt][0][lane] = accm; red[jt][1][lane] = accl; }
    __syncthreads();
    if (kh == 0) {
        accm += red[jt][0][lane]; accl += red[jt][1][lane];
        #pragma unroll
        for (int i = 0; i < 4; ++i) {
            const int n = nb + quad * 4 + i;
            float mu = accm[i] + P.mub[jcol];
            float lv = accl[i] + P.lvb[jcol];
            float e = mu + expf(0.5f * lv) * P.eps[(size_t)n * LL + jcol];
            P.hdecAf[(size_t)n * LL + jcol] = e;
            P.hdecAb[(size_t)n * LL + jcol] = f2bf(e);
        }
    }
}

// ---------------------------------------------------------------- MFMA decoder head: 16 samples/block
// y1=relu(h@d1W^T) [16,128]; y2=relu(y1@d2W^T) [16,64]; y3=y2@d3W^T [16,128]; masked L1 vs s_next_roll
__device__ void head_tile(const PParams& P, const int hb, const int tid,
                          const unsigned short* __restrict__ h_bf, int ti,
                          unsigned short (&ylds)[16][136], unsigned short (&y2lds)[16][72],
                          float (&lred)[4])
{
    const int lane = tid & 63, w = tid >> 6;
    const int m16 = lane & 15, quad = lane >> 4;
    const int n0 = hb * 16;

    // ---- y1: K=1024, 8 j-tiles, wave w -> tiles {2w, 2w+1}
    #pragma unroll
    for (int jt = 0; jt < 2; ++jt) {
        const int c0 = (w * 2 + jt) * 16;
        f32x4 acc{};
        const unsigned short* ap = h_bf  + (size_t)(n0 + m16) * LL + quad * 8;
        const unsigned short* bp = P.d1Wb + (size_t)(c0 + m16) * LL + quad * 8;
        #pragma unroll 4
        for (int c = 0; c < 32; ++c) {
            bf16x8 av = *(const bf16x8*)(ap + c * 32);
            bf16x8 bv = *(const bf16x8*)(bp + c * 32);
            acc = __builtin_amdgcn_mfma_f32_16x16x32_bf16(av, bv, acc, 0, 0, 0);
        }
        const float b = P.d1b[c0 + m16];
        #pragma unroll
        for (int i = 0; i < 4; ++i)
            ylds[quad * 4 + i][c0 + m16] = f2bf(fmaxf(acc[i] + b, 0.0f));
    }
    __syncthreads();

    // ---- y2: K=128, 4 j-tiles, wave w -> tile w
    {
        const int c0 = w * 16;
        f32x4 acc{};
        #pragma unroll
        for (int c = 0; c < 4; ++c) {
            bf16x8 av = *(const bf16x8*)&ylds[m16][c * 32 + quad * 8];
            bf16x8 bv = *(const bf16x8*)(P.d2Wb + (size_t)(c0 + m16) * 128 + c * 32 + quad * 8);
            acc = __builtin_amdgcn_mfma_f32_16x16x32_bf16(av, bv, acc, 0, 0, 0);
        }
        const float b = P.d2b[c0 + m16];
        #pragma unroll
        for (int i = 0; i < 4; ++i)
            y2lds[quad * 4 + i][c0 + m16] = f2bf(fmaxf(acc[i] + b, 0.0f));
    }
    __syncthreads();

    // ---- y3: K=64, 8 j-tiles, wave w -> tiles {2w, 2w+1}; fused masked L1
    float lsum = 0.0f;
    #pragma unroll
    for (int jt = 0; jt < 2; ++jt) {
        const int c0 = (w * 2 + jt) * 16;
        f32x4 acc{};
        #pragma unroll
        for (int c = 0; c < 2; ++c) {
            bf16x8 av = *(const bf16x8*)&y2lds[m16][c * 32 + quad * 8];
            bf16x8 bv = *(const bf16x8*)(P.d3Wb + (size_t)(c0 + m16) * 64 + c * 32 + quad * 8);
            acc = __builtin_amdgcn_mfma_f32_16x16x32_bf16(av, bv, acc, 0, 0, 0);
        }
        const int col = c0 + m16;
        const float b = P.d3b[col];
        #pragma unroll
        for (int i = 0; i < 4; ++i) {
            const int n = n0 + quad * 4 + i;
            if (ti < P.limitv[n]) {
                int tr = ti + P.startv[n]; if (tr >= TT) tr -= TT;
                float v = P.s_next[(size_t)n * TT * SS + (size_t)tr * SS + col];
                lsum += fabsf(v - (acc[i] + b));
            }
        }
    }
    for (int off = 32; off >= 1; off >>= 1) lsum += __shfl_down(lsum, off);
    if (lane == 0) lred[w] = lsum;
    __syncthreads();
    if (tid == 0) atomicAdd(P.loss, lred[0] + lred[1] + lred[2] + lred[3]);
}

// ---------------------------------------------------------------- the persistent kernel
__global__ __launch_bounds__(256, 2)
void persist(PParams P)
{
    __shared__ f32x4 red[2][4][64];                 // 8 KB matmul split-K
    __shared__ __align__(16) unsigned short ylds[16][136];
    __shared__ __align__(16) unsigned short y2lds[16][72];
    __shared__ float lred[4];
    __shared__ int mint;
    __shared__ int wml[4], wme[4];
    const int bid = blockIdx.x, tid = threadIdx.x;
    int gen = 0;

    // ================= phase 0: cast, split detection, h0, adec, loss=0
    {
        const long N0 = 3072L * 160, N1 = N0 + 3072L * 1024, N2 = N1 + 3072L * 32,
                   N3 = N2 + 3072L * 1024, N4 = N3 + 1048576L, N5 = N4 + 1048576L,
                   N6 = N5 + 128L * 100 * 160, N7 = N6 + 131072L, N8 = N7 + 8192L,
                   N9 = N8 + 8192L;
        for (long i = (long)bid * 256 + tid; i < N9; i += (long)NBLK * 256) {
            if (i < N0)      P.eWih_b[i]      = f2bf(P.eWih[i]);
            else if (i < N1) P.eWhh_b[i - N0] = f2bf(P.eWhh[i - N0]);
            else if (i < N2) P.dWih_b[i - N1] = f2bf(P.dWih[i - N1]);
            else if (i < N3) P.dWhh_b[i - N2] = f2bf(P.dWhh[i - N2]);
            else if (i < N4) P.mlW_b[i - N3]  = f2bf(P.muW[i - N3]);
            else if (i < N5) P.mlW_b[1048576L + (i - N4)] = f2bf(P.lvW[i - N4]);
            else if (i < N6) {
                long j = i - N5;                  // n*16000 + t*160 + k
                int  k = (int)(j % 160);
                long nt = j / 160;
                int  t = (int)(nt % 100), n = (int)(nt / 100);
                float v = (k < SS) ? P.s[(size_t)n * TT * SS + (size_t)t * SS + k]
                                   : P.a[(size_t)n * TT * AA + (size_t)t * AA + (k - SS)];
                P.xenc_b[j] = f2bf(v);
            }
            else if (i < N7) P.d1Wb[i - N6] = f2bf(P.d1W[i - N6]);
            else if (i < N8) P.d2Wb[i - N7] = f2bf(P.d2W[i - N7]);
            else             P.d3Wb[i - N8] = f2bf(P.d3W[i - N8]);
        }
    }
    if (bid < NN_) {
        const int n = bid;
        if (tid == 0) mint = TT - 1;
        __syncthreads();
        int t = tid + 1;
        if (t < TT && tid < 128) {
            const float* row = P.s + (size_t)n * TT * SS + (size_t)t * SS;
            bool allz = true;
            for (int i = 0; i < SS; ++i) { if (row[i] != 0.0f) { allz = false; break; } }
            if (allz) atomicMin(&mint, t);
        }
        __syncthreads();
        const int m = mint, st = m + 1;
        if (tid == 0) { P.endv[n] = m - 1; P.startv[n] = st; P.limitv[n] = TT - 1 - m; }
        for (int idx = tid; idx < LL; idx += 256) {
            P.hencAf[(size_t)n * LL + idx] = 1.0f;
            P.hencAb[(size_t)n * LL + idx] = 0x3F80;
        }
        for (int idx = tid; idx < 50 * AA; idx += 256) {
            int i = idx >> 5, k = idx & 31;
            int tr = i + st; if (tr >= TT) tr -= TT;
            P.adec_b[(size_t)n * (50 * AA) + idx] =
                f2bf(P.a[(size_t)n * TT * AA + (size_t)tr * AA + k]);
        }
    }
    gbar(P.bar, bid, tid, ++gen);

    // ================= phase 0.5: all blocks compute ME = max(end), ML = max(limit)
    int ME, ML;
    {
        int lv = 0, ev = 0;
        if (tid < NN_) { lv = P.limitv[tid]; ev = P.endv[tid]; }
        for (int off = 32; off >= 1; off >>= 1) {
            lv = max(lv, __shfl_down(lv, off));
            ev = max(ev, __shfl_down(ev, off));
        }
        if ((tid & 63) == 0) { wml[tid >> 6] = lv; wme[tid >> 6] = ev; }
        __syncthreads();
        ML = max(max(wml[0], wml[1]), max(wml[2], wml[3]));
        ME = max(max(wme[0], wme[1]), max(wme[2], wme[3]));
        __syncthreads();
    }

    // ================= encoder: t = 0..ME (<= 97)
    for (int t = 0; t <= ME; ++t) {
        if (bid < 256) {
            const unsigned short* hib = (t & 1) ? P.hencBb : P.hencAb;
            const float*          hif = (t & 1) ? P.hencBf : P.hencAf;
            float*          hof = (t & 1) ? P.hencAf : P.hencBf;
            unsigned short* hob = (t & 1) ? P.hencAb : P.hencBb;
            gru_tile<160, false>(bid, tid, hib, hif, hof, hob,
                                 P.eWhh_b, P.eWih_b, P.xenc_b, P.ebih, P.ebhh,
                                 P.endv, P.hf_bf, t, red);
        }
        gbar(P.bar, bid, tid, ++gen);
    }

    // ================= reparametrize
    if (bid < 256) emb_tile(P, bid, tid, red);
    gbar(P.bar, bid, tid, ++gen);

    // ================= decoder: i = 0..ML; matmul (i<ML) overlaps head for step i-1
    for (int i = 0; i <= ML; ++i) {
        const unsigned short* hib = (i & 1) ? P.hdecBb : P.hdecAb;
        if (bid < 256) {
            if (i < ML) {
                const float* hif = (i & 1) ? P.hdecBf : P.hdecAf;
                float*          hof = (i & 1) ? P.hdecAf : P.hdecBf;
                unsigned short* hob = (i & 1) ? P.hdecAb : P.hdecBb;
                gru_tile<32, true>(bid, tid, hib, hif, hof, hob,
                                   P.dWhh_b, P.dWih_b, P.adec_b, P.dbih, P.dbhh,
                                   nullptr, nullptr, i, red);
            }
        } else if (i >= 1) {
            head_tile(P, bid - 256, tid, hib, i - 1, ylds, y2lds, lred);
        }
        gbar(P.bar, bid, tid, ++gen);
    }
}

// ---------------------------------------------------------------- launch
extern "C" void kernel_launch(void* const* d_in, const int* in_sizes, int n_in,
                              void* d_out, int out_size, void* d_ws, size_t ws_size,
                              hipStream_t stream) {
    PParams P;
    P.s      = (const float*)d_in[0];
    P.a      = (const float*)d_in[1];
    P.s_next = (const float*)d_in[3];
    P.eps    = (const float*)d_in[4];
    P.eWih   = (const float*)d_in[5];
    P.eWhh   = (const float*)d_in[6];
    P.ebih   = (const float*)d_in[7];
    P.ebhh   = (const float*)d_in[8];
    P.muW    = (const float*)d_in[9];
    P.mub    = (const float*)d_in[10];
    P.lvW    = (const float*)d_in[11];
    P.lvb    = (const float*)d_in[12];
    // st1..st3 (13..18) dead code w.r.t. the loss
    P.dWih   = (const float*)d_in[19];
    P.dWhh   = (const float*)d_in[20];
    P.dbih   = (const float*)d_in[21];
    P.dbhh   = (const float*)d_in[22];
    P.d1W    = (const float*)d_in[23];
    P.d1b    = (const float*)d_in[24];
    P.d2W    = (const float*)d_in[25];
    P.d2b    = (const float*)d_in[26];
    P.d3W    = (const float*)d_in[27];
    P.d3b    = (const float*)d_in[28];
    P.loss   = (float*)d_out;

    char* p = (char*)d_ws;
    P.bar    = (int*)p;                    p += 20480;   // barrier state (5120 ints zeroed)
    P.endv   = (int*)p;                    p += 512;
    P.startv = (int*)p;                    p += 512;
    P.limitv = (int*)p;                    p += 512;
    p += 2560;                             // pad
    P.hencAf = (float*)p;                  p += 128 * 1024 * 4;
    P.hencBf = (float*)p;                  p += 128 * 1024 * 4;
    P.hdecAf = (float*)p;                  p += 128 * 1024 * 4;
    P.hdecBf = (float*)p;                  p += 128 * 1024 * 4;
    P.hencAb = (unsigned short*)p;         p += 128 * 1024 * 2;
    P.hencBb = (unsigned short*)p;         p += 128 * 1024 * 2;
    P.hdecAb = (unsigned short*)p;         p += 128 * 1024 * 2;
    P.hdecBb = (unsigned short*)p;         p += 128 * 1024 * 2;
    P.hf_bf  = (unsigned short*)p;         p += 128 * 1024 * 2;
    P.eWih_b = (unsigned short*)p;         p += 3072 * 160 * 2;
    P.eWhh_b = (unsigned short*)p;         p += 3072 * 1024 * 2;
    P.dWih_b = (unsigned short*)p;         p += 3072 * 32 * 2;
    P.dWhh_b = (unsigned short*)p;         p += 3072 * 1024 * 2;
    P.mlW_b  = (unsigned short*)p;         p += 2048 * 1024 * 2;
    P.xenc_b = (unsigned short*)p;         p += 128 * 100 * 160 * 2;
    P.adec_b = (unsigned short*)p;         p += 128 * 50 * 32 * 2;
    P.d1Wb   = (unsigned short*)p;         p += 128 * 1024 * 2;
    P.d2Wb   = (unsigned short*)p;         p += 64 * 128 * 2;
    P.d3Wb   = (unsigned short*)p;         p += 128 * 64 * 2;

    hipLaunchKernelGGL(init_kernel, dim3(1), dim3(256), 0, stream, P.bar, P.loss);
    hipLaunchKernelGGL(persist, dim3(NBLK), dim3(256), 0, stream, P);
}

// Round 6
// 3625.092 us; speedup vs baseline: 5.2551x; 1.2088x over previous
//
#include <hip/hip_runtime.h>
#include <math.h>

#define NN_ 128   // batch
#define TT  100   // time steps
#define SS  128   // state dim
#define AA  32    // action dim
#define LL  1024  // hidden (= Z)
#define NBLK 264  // 256 matmul tiles + 8 head blocks

typedef __attribute__((ext_vector_type(8))) short bf16x8;   // 8 bf16 in 4 VGPRs
typedef __attribute__((ext_vector_type(4))) float f32x4;

__device__ __forceinline__ float sigmoidf_(float x) { return 1.0f / (1.0f + expf(-x)); }
__device__ __forceinline__ unsigned short f2bf(float x) {
    union { float f; unsigned u; } v; v.f = x;
    return (unsigned short)((v.u + 0x7fffu + ((v.u >> 16) & 1u)) >> 16);   // RNE
}

// ---- agent-scope (LLC-coherent, L2-bypassing) access helpers
__device__ __forceinline__ bf16x8 lda16(const unsigned short* p) {   // 16B via 2x8B agent loads
    union { bf16x8 v; unsigned long long q[2]; } u;
    u.q[0] = __hip_atomic_load((const unsigned long long*)p,     __ATOMIC_RELAXED, __HIP_MEMORY_SCOPE_AGENT);
    u.q[1] = __hip_atomic_load((const unsigned long long*)p + 1, __ATOMIC_RELAXED, __HIP_MEMORY_SCOPE_AGENT);
    return u.v;
}
__device__ __forceinline__ void sta2(unsigned short* p, unsigned short v) {
    __hip_atomic_store(p, v, __ATOMIC_RELAXED, __HIP_MEMORY_SCOPE_AGENT);
}

struct PParams {
    const float *s, *a, *s_next, *eps;
    const float *eWih, *eWhh, *ebih, *ebhh;
    const float *muW, *mub, *lvW, *lvb;
    const float *dWih, *dWhh, *dbih, *dbhh;
    const float *d1W, *d1b, *d2W, *d2b, *d3W, *d3b;
    int *bar;
    int *endv, *startv, *limitv;
    unsigned short *hencAb, *hencBb, *hdecAb, *hdecBb, *hf_bf;
    unsigned short *eWih_b, *eWhh_b, *dWih_b, *dWhh_b, *mlW_b, *xenc_b, *adec_b;
    unsigned short *d1Wb, *d2Wb, *d3Wb;
    float *loss;
};

// ---------------------------------------------------------------- grid barriers
// bar ints: [g*16] 8 group counters; [128] master; [132] broken; [144+g*16] 8 group flags.
// Monotone counters; gen starts at 1. Steady-state data (h) flows via sc1/LLC, so the
// light barrier needs NO cache writeback/invalidate — just waitcnt + counter + flag.
__device__ void gbar_lite(int* bar, int bid, int tid, int gen) {
    __syncthreads();
    if (tid == 0) {
        __builtin_amdgcn_s_waitcnt(0);   // all prior (sc1) stores ACKed at LLC
        if (__hip_atomic_load(bar + 132, __ATOMIC_RELAXED, __HIP_MEMORY_SCOPE_AGENT) == 0) {
            const int g = bid & 7;
            int pos = __hip_atomic_fetch_add(bar + g * 16, 1, __ATOMIC_RELAXED, __HIP_MEMORY_SCOPE_AGENT);
            if (pos + 1 == (NBLK / 8) * gen) {
                int mp = __hip_atomic_fetch_add(bar + 128, 1, __ATOMIC_RELAXED, __HIP_MEMORY_SCOPE_AGENT);
                if (mp + 1 == 8 * gen) {
                    for (int b = 0; b < 8; ++b)
                        __hip_atomic_store(bar + 144 + b * 16, gen, __ATOMIC_RELAXED, __HIP_MEMORY_SCOPE_AGENT);
                }
            }
            int it = 0;
            while (__hip_atomic_load(bar + 144 + g * 16, __ATOMIC_RELAXED, __HIP_MEMORY_SCOPE_AGENT) < gen) {
                __builtin_amdgcn_s_sleep(1);
                if (++it > 4000000) {   // safety valve (~1s)
                    __hip_atomic_store(bar + 132, 1, __ATOMIC_RELAXED, __HIP_MEMORY_SCOPE_AGENT);
                    break;
                }
            }
        }
    }
    __syncthreads();
}
// Heavy barrier (one-time, after phase-0 plain-store cast): full L2 writeback + invalidate.
__device__ void gbar_heavy(int* bar, int bid, int tid, int gen) {
    __syncthreads();
    if (tid == 0) __threadfence();      // wbl2: flush cast weights to LLC
    gbar_lite(bar, bid, tid, gen);
    if (tid == 0) __threadfence();      // inv: drop any stale lines
    __syncthreads();
}

// ---------------------------------------------------------------- init (separate launch)
__global__ void init_kernel(int* bar, float* loss) {
    for (int i = threadIdx.x; i < 5120; i += 256) bar[i] = 0;
    if (threadIdx.x == 0) loss[0] = 0.0f;
}

// ---------------------------------------------------------------- GRU step matmul tile
// 256 tiles: 8 n-blocks x 32 j-blocks(32 wide); 4 waves = 2 j-tiles x 2 K-halves.
// fp32 h state lives in `hold` registers of the kh==0 waves (same lane <-> same (n,jcol) forever).
template<int XK, bool IS_DEC>
__device__ void gru_tile(const int bid, const int tid,
    const unsigned short* __restrict__ h_bf, unsigned short* __restrict__ ho_bf,
    const unsigned short* __restrict__ Whh_b, const unsigned short* __restrict__ Wih_b,
    const unsigned short* __restrict__ x_bf,
    const float* __restrict__ bih, const float* __restrict__ bhh,
    const int* __restrict__ endv, unsigned short* __restrict__ hf_bf,
    int t, f32x4 (&red)[2][4][64], f32x4& hold)
{
    const int lane = tid & 63, w = tid >> 6;
    const int jt = w & 1, kh = w >> 1;
    const int m = lane & 15, quad = lane >> 4;
    const int nb = (bid >> 5) << 4;            // 0..112 step 16
    const int jb = (bid & 31) * 32 + jt * 16;  // 0..1008 step 16
    const int jcol = jb + m;

    f32x4 accr{}, accz{}, acchn{}, accxn{};

    {   // hidden: K = 1024, 32 chunks, split 16/16 across kh; h via agent(LLC) loads
        const unsigned short* ap  = h_bf + (size_t)(nb + m) * LL + quad * 8;
        const unsigned short* brp = Whh_b + (size_t)(0 * LL + jcol) * LL + quad * 8;
        const unsigned short* bzp = Whh_b + (size_t)(1 * LL + jcol) * LL + quad * 8;
        const unsigned short* bnp = Whh_b + (size_t)(2 * LL + jcol) * LL + quad * 8;
        #pragma unroll 4
        for (int c = kh * 16; c < kh * 16 + 16; ++c) {
            const int k0 = c * 32;
            bf16x8 av = lda16(ap + k0);
            bf16x8 br = *(const bf16x8*)(brp + k0);
            bf16x8 bz = *(const bf16x8*)(bzp + k0);
            bf16x8 bn = *(const bf16x8*)(bnp + k0);
            accr  = __builtin_amdgcn_mfma_f32_16x16x32_bf16(av, br, accr, 0, 0, 0);
            accz  = __builtin_amdgcn_mfma_f32_16x16x32_bf16(av, bz, accz, 0, 0, 0);
            acchn = __builtin_amdgcn_mfma_f32_16x16x32_bf16(av, bn, acchn, 0, 0, 0);
        }
    }
    {   // input: K = XK (enc 160, dec 32); read-only -> plain L2-cached loads
        const int XC = XK / 32, XC0 = (XC + 1) / 2;
        const size_t xstride = IS_DEC ? (size_t)(50 * AA) : (size_t)(TT * (SS + AA));
        const unsigned short* xp  = x_bf + (size_t)(nb + m) * xstride + (size_t)t * XK + quad * 8;
        const unsigned short* brp = Wih_b + (size_t)(0 * LL + jcol) * XK + quad * 8;
        const unsigned short* bzp = Wih_b + (size_t)(1 * LL + jcol) * XK + quad * 8;
        const unsigned short* bnp = Wih_b + (size_t)(2 * LL + jcol) * XK + quad * 8;
        #pragma unroll
        for (int c = (kh ? XC0 : 0); c < (kh ? XC : XC0); ++c) {
            const int k0 = c * 32;
            bf16x8 av = *(const bf16x8*)(xp + k0);
            bf16x8 br = *(const bf16x8*)(brp + k0);
            bf16x8 bz = *(const bf16x8*)(bzp + k0);
            bf16x8 bn = *(const bf16x8*)(bnp + k0);
            accr  = __builtin_amdgcn_mfma_f32_16x16x32_bf16(av, br, accr, 0, 0, 0);
            accz  = __builtin_amdgcn_mfma_f32_16x16x32_bf16(av, bz, accz, 0, 0, 0);
            accxn = __builtin_amdgcn_mfma_f32_16x16x32_bf16(av, bn, accxn, 0, 0, 0);
        }
    }
    if (kh == 1) {
        red[jt][0][lane] = accr;  red[jt][1][lane] = accz;
        red[jt][2][lane] = acchn; red[jt][3][lane] = accxn;
    }
    __syncthreads();
    if (kh == 0) {
        accr  += red[jt][0][lane];  accz  += red[jt][1][lane];
        acchn += red[jt][2][lane];  accxn += red[jt][3][lane];
        const float br_  = bih[jcol] + bhh[jcol];
        const float bz_  = bih[LL + jcol] + bhh[LL + jcol];
        const float bxn_ = bih[2 * LL + jcol];
        const float bhn_ = bhh[2 * LL + jcol];
        #pragma unroll
        for (int i = 0; i < 4; ++i) {
            const int n = nb + quad * 4 + i;     // C layout: row = quad*4+reg, col = lane&15
            float r = sigmoidf_(accr[i] + br_);
            float z = sigmoidf_(accz[i] + bz_);
            float g = tanhf(accxn[i] + bxn_ + r * (acchn[i] + bhn_));
            float hn = (1.0f - z) * g + z * hold[i];
            hold[i] = hn;
            sta2(ho_bf + (size_t)n * LL + jcol, f2bf(hn));
            if (!IS_DEC) { if (endv[n] == t) sta2(hf_bf + (size_t)n * LL + jcol, f2bf(hn)); }
        }
    }
}

// ---------------------------------------------------------------- reparametrize tile -> hold regs + bf16
__device__ void emb_tile(const PParams& P, const int bid, const int tid,
                         f32x4 (&red)[2][4][64], f32x4& hold)
{
    const int lane = tid & 63, w = tid >> 6;
    const int jt = w & 1, kh = w >> 1;
    const int m = lane & 15, quad = lane >> 4;
    const int nb = (bid >> 5) << 4;
    const int jb = (bid & 31) * 32 + jt * 16;
    const int jcol = jb + m;
    f32x4 accm{}, accl{};
    const unsigned short* ap  = P.hf_bf + (size_t)(nb + m) * LL + quad * 8;
    const unsigned short* bmp = P.mlW_b + (size_t)jcol * LL + quad * 8;
    const unsigned short* blp = P.mlW_b + (size_t)(LL + jcol) * LL + quad * 8;
    #pragma unroll 4
    for (int c = kh * 16; c < kh * 16 + 16; ++c) {
        const int k0 = c * 32;
        bf16x8 av = lda16(ap + k0);
        bf16x8 bm = *(const bf16x8*)(bmp + k0);
        bf16x8 bl = *(const bf16x8*)(blp + k0);
        accm = __builtin_amdgcn_mfma_f32_16x16x32_bf16(av, bm, accm, 0, 0, 0);
        accl = __builtin_amdgcn_mfma_f32_16x16x32_bf16(av, bl, accl, 0, 0, 0);
    }
    if (kh == 1) { red[jt][0][lane] = accm; red[jt][1][lane] = accl; }
    __syncthreads();
    if (kh == 0) {
        accm += red[jt][0][lane]; accl += red[jt][1][lane];
        #pragma unroll
        for (int i = 0; i < 4; ++i) {
            const int n = nb + quad * 4 + i;
            float mu = accm[i] + P.mub[jcol];
            float lv = accl[i] + P.lvb[jcol];
            float e = mu + expf(0.5f * lv) * P.eps[(size_t)n * LL + jcol];
            hold[i] = e;
            sta2(P.hdecAb + (size_t)n * LL + jcol, f2bf(e));
        }
    }
}

// ---------------------------------------------------------------- MFMA decoder head: 16 samples/block
__device__ void head_tile(const PParams& P, const int hb, const int tid,
                          const unsigned short* __restrict__ h_bf, int ti,
                          unsigned short (&ylds)[16][136], unsigned short (&y2lds)[16][72],
                          float (&lred)[4])
{
    const int lane = tid & 63, w = tid >> 6;
    const int m16 = lane & 15, quad = lane >> 4;
    const int n0 = hb * 16;

    // ---- y1: K=1024, 8 j-tiles, wave w -> tiles {2w, 2w+1}
    #pragma unroll
    for (int jt = 0; jt < 2; ++jt) {
        const int c0 = (w * 2 + jt) * 16;
        f32x4 acc{};
        const unsigned short* ap = h_bf  + (size_t)(n0 + m16) * LL + quad * 8;
        const unsigned short* bp = P.d1Wb + (size_t)(c0 + m16) * LL + quad * 8;
        #pragma unroll 4
        for (int c = 0; c < 32; ++c) {
            bf16x8 av = lda16(ap + c * 32);
            bf16x8 bv = *(const bf16x8*)(bp + c * 32);
            acc = __builtin_amdgcn_mfma_f32_16x16x32_bf16(av, bv, acc, 0, 0, 0);
        }
        const float b = P.d1b[c0 + m16];
        #pragma unroll
        for (int i = 0; i < 4; ++i)
            ylds[quad * 4 + i][c0 + m16] = f2bf(fmaxf(acc[i] + b, 0.0f));
    }
    __syncthreads();

    // ---- y2: K=128, 4 j-tiles, wave w -> tile w
    {
        const int c0 = w * 16;
        f32x4 acc{};
        #pragma unroll
        for (int c = 0; c < 4; ++c) {
            bf16x8 av = *(const bf16x8*)&ylds[m16][c * 32 + quad * 8];
            bf16x8 bv = *(const bf16x8*)(P.d2Wb + (size_t)(c0 + m16) * 128 + c * 32 + quad * 8);
            acc = __builtin_amdgcn_mfma_f32_16x16x32_bf16(av, bv, acc, 0, 0, 0);
        }
        const float b = P.d2b[c0 + m16];
        #pragma unroll
        for (int i = 0; i < 4; ++i)
            y2lds[quad * 4 + i][c0 + m16] = f2bf(fmaxf(acc[i] + b, 0.0f));
    }
    __syncthreads();

    // ---- y3: K=64, 8 j-tiles; fused masked L1
    float lsum = 0.0f;
    #pragma unroll
    for (int jt = 0; jt < 2; ++jt) {
        const int c0 = (w * 2 + jt) * 16;
        f32x4 acc{};
        #pragma unroll
        for (int c = 0; c < 2; ++c) {
            bf16x8 av = *(const bf16x8*)&y2lds[m16][c * 32 + quad * 8];
            bf16x8 bv = *(const bf16x8*)(P.d3Wb + (size_t)(c0 + m16) * 64 + c * 32 + quad * 8);
            acc = __builtin_amdgcn_mfma_f32_16x16x32_bf16(av, bv, acc, 0, 0, 0);
        }
        const int col = c0 + m16;
        const float b = P.d3b[col];
        #pragma unroll
        for (int i = 0; i < 4; ++i) {
            const int n = n0 + quad * 4 + i;
            if (ti < P.limitv[n]) {
                int tr = ti + P.startv[n]; if (tr >= TT) tr -= TT;
                float v = P.s_next[(size_t)n * TT * SS + (size_t)tr * SS + col];
                lsum += fabsf(v - (acc[i] + b));
            }
        }
    }
    for (int off = 32; off >= 1; off >>= 1) lsum += __shfl_down(lsum, off);
    if (lane == 0) lred[w] = lsum;
    __syncthreads();
    if (tid == 0) atomicAdd(P.loss, lred[0] + lred[1] + lred[2] + lred[3]);
}

// ---------------------------------------------------------------- the persistent kernel
__global__ __launch_bounds__(256, 2)
void persist(PParams P)
{
    __shared__ f32x4 red[2][4][64];                 // 8 KB matmul split-K
    __shared__ __align__(16) unsigned short ylds[16][136];
    __shared__ __align__(16) unsigned short y2lds[16][72];
    __shared__ float lred[4];
    __shared__ int mint;
    __shared__ int wml[4], wme[4];
    const int bid = blockIdx.x, tid = threadIdx.x;
    int gen = 0;

    // ================= phase 0: cast (plain stores), split detection, h0, adec
    {
        const long N0 = 3072L * 160, N1 = N0 + 3072L * 1024, N2 = N1 + 3072L * 32,
                   N3 = N2 + 3072L * 1024, N4 = N3 + 1048576L, N5 = N4 + 1048576L,
                   N6 = N5 + 128L * 100 * 160, N7 = N6 + 131072L, N8 = N7 + 8192L,
                   N9 = N8 + 8192L;
        for (long i = (long)bid * 256 + tid; i < N9; i += (long)NBLK * 256) {
            if (i < N0)      P.eWih_b[i]      = f2bf(P.eWih[i]);
            else if (i < N1) P.eWhh_b[i - N0] = f2bf(P.eWhh[i - N0]);
            else if (i < N2) P.dWih_b[i - N1] = f2bf(P.dWih[i - N1]);
            else if (i < N3) P.dWhh_b[i - N2] = f2bf(P.dWhh[i - N2]);
            else if (i < N4) P.mlW_b[i - N3]  = f2bf(P.muW[i - N3]);
            else if (i < N5) P.mlW_b[1048576L + (i - N4)] = f2bf(P.lvW[i - N4]);
            else if (i < N6) {
                long j = i - N5;                  // n*16000 + t*160 + k
                int  k = (int)(j % 160);
                long nt = j / 160;
                int  t = (int)(nt % 100), n = (int)(nt / 100);
                float v = (k < SS) ? P.s[(size_t)n * TT * SS + (size_t)t * SS + k]
                                   : P.a[(size_t)n * TT * AA + (size_t)t * AA + (k - SS)];
                P.xenc_b[j] = f2bf(v);
            }
            else if (i < N7) P.d1Wb[i - N6] = f2bf(P.d1W[i - N6]);
            else if (i < N8) P.d2Wb[i - N7] = f2bf(P.d2W[i - N7]);
            else             P.d3Wb[i - N8] = f2bf(P.d3W[i - N8]);
        }
    }
    if (bid < NN_) {
        const int n = bid;
        if (tid == 0) mint = TT - 1;
        __syncthreads();
        int t = tid + 1;
        if (t < TT && tid < 128) {
            const float* row = P.s + (size_t)n * TT * SS + (size_t)t * SS;
            bool allz = true;
            for (int i = 0; i < SS; ++i) { if (row[i] != 0.0f) { allz = false; break; } }
            if (allz) atomicMin(&mint, t);
        }
        __syncthreads();
        const int m = mint, st = m + 1;
        if (tid == 0) { P.endv[n] = m - 1; P.startv[n] = st; P.limitv[n] = TT - 1 - m; }
        for (int idx = tid; idx < LL; idx += 256)
            P.hencAb[(size_t)n * LL + idx] = 0x3F80;   // bf16 1.0
        for (int idx = tid; idx < 50 * AA; idx += 256) {
            int i = idx >> 5, k = idx & 31;
            int tr = i + st; if (tr >= TT) tr -= TT;
            P.adec_b[(size_t)n * (50 * AA) + idx] =
                f2bf(P.a[(size_t)n * TT * AA + (size_t)tr * AA + k]);
        }
    }
    gbar_heavy(P.bar, bid, tid, ++gen);

    // ================= phase 0.5: all blocks compute ME = max(end), ML = max(limit)
    int ME, ML;
    {
        int lv = 0, ev = 0;
        if (tid < NN_) { lv = P.limitv[tid]; ev = P.endv[tid]; }
        for (int off = 32; off >= 1; off >>= 1) {
            lv = max(lv, __shfl_down(lv, off));
            ev = max(ev, __shfl_down(ev, off));
        }
        if ((tid & 63) == 0) { wml[tid >> 6] = lv; wme[tid >> 6] = ev; }
        __syncthreads();
        ML = max(max(wml[0], wml[1]), max(wml[2], wml[3]));
        ME = max(max(wme[0], wme[1]), max(wme[2], wme[3]));
        __syncthreads();
    }

    f32x4 hold = { 1.0f, 1.0f, 1.0f, 1.0f };   // enc h0 = ones (fp32 state lives here)

    // ================= encoder: t = 0..ME (<= 97)
    for (int t = 0; t <= ME; ++t) {
        if (bid < 256) {
            const unsigned short* hib = (t & 1) ? P.hencBb : P.hencAb;
            unsigned short*       hob = (t & 1) ? P.hencAb : P.hencBb;
            gru_tile<160, false>(bid, tid, hib, hob,
                                 P.eWhh_b, P.eWih_b, P.xenc_b, P.ebih, P.ebhh,
                                 P.endv, P.hf_bf, t, red, hold);
        }
        gbar_lite(P.bar, bid, tid, ++gen);
    }

    // ================= reparametrize (deposits decoder h0 into hold regs)
    if (bid < 256) emb_tile(P, bid, tid, red, hold);
    gbar_lite(P.bar, bid, tid, ++gen);

    // ================= decoder: i = 0..ML; matmul (i<ML) overlaps head for step i-1
    for (int i = 0; i <= ML; ++i) {
        const unsigned short* hib = (i & 1) ? P.hdecBb : P.hdecAb;
        if (bid < 256) {
            if (i < ML) {
                unsigned short* hob = (i & 1) ? P.hdecAb : P.hdecBb;
                gru_tile<32, true>(bid, tid, hib, hob,
                                   P.dWhh_b, P.dWih_b, P.adec_b, P.dbih, P.dbhh,
                                   nullptr, nullptr, i, red, hold);
            }
        } else if (i >= 1) {
            head_tile(P, bid - 256, tid, hib, i - 1, ylds, y2lds, lred);
        }
        gbar_lite(P.bar, bid, tid, ++gen);
    }
}

// ---------------------------------------------------------------- launch
extern "C" void kernel_launch(void* const* d_in, const int* in_sizes, int n_in,
                              void* d_out, int out_size, void* d_ws, size_t ws_size,
                              hipStream_t stream) {
    PParams P;
    P.s      = (const float*)d_in[0];
    P.a      = (const float*)d_in[1];
    P.s_next = (const float*)d_in[3];
    P.eps    = (const float*)d_in[4];
    P.eWih   = (const float*)d_in[5];
    P.eWhh   = (const float*)d_in[6];
    P.ebih   = (const float*)d_in[7];
    P.ebhh   = (const float*)d_in[8];
    P.muW    = (const float*)d_in[9];
    P.mub    = (const float*)d_in[10];
    P.lvW    = (const float*)d_in[11];
    P.lvb    = (const float*)d_in[12];
    // st1..st3 (13..18) dead code w.r.t. the loss
    P.dWih   = (const float*)d_in[19];
    P.dWhh   = (const float*)d_in[20];
    P.dbih   = (const float*)d_in[21];
    P.dbhh   = (const float*)d_in[22];
    P.d1W    = (const float*)d_in[23];
    P.d1b    = (const float*)d_in[24];
    P.d2W    = (const float*)d_in[25];
    P.d2b    = (const float*)d_in[26];
    P.d3W    = (const float*)d_in[27];
    P.d3b    = (const float*)d_in[28];
    P.loss   = (float*)d_out;

    char* p = (char*)d_ws;
    P.bar    = (int*)p;                    p += 20480;
    P.endv   = (int*)p;                    p += 512;
    P.startv = (int*)p;                    p += 512;
    P.limitv = (int*)p;                    p += 512;
    p += 2560;                             // pad
    P.hencAb = (unsigned short*)p;         p += 128 * 1024 * 2;
    P.hencBb = (unsigned short*)p;         p += 128 * 1024 * 2;
    P.hdecAb = (unsigned short*)p;         p += 128 * 1024 * 2;
    P.hdecBb = (unsigned short*)p;         p += 128 * 1024 * 2;
    P.hf_bf  = (unsigned short*)p;         p += 128 * 1024 * 2;
    P.eWih_b = (unsigned short*)p;         p += 3072 * 160 * 2;
    P.eWhh_b = (unsigned short*)p;         p += 3072 * 1024 * 2;
    P.dWih_b = (unsigned short*)p;         p += 3072 * 32 * 2;
    P.dWhh_b = (unsigned short*)p;         p += 3072 * 1024 * 2;
    P.mlW_b  = (unsigned short*)p;         p += 2048 * 1024 * 2;
    P.xenc_b = (unsigned short*)p;         p += 128 * 100 * 160 * 2;
    P.adec_b = (unsigned short*)p;         p += 128 * 50 * 32 * 2;
    P.d1Wb   = (unsigned short*)p;         p += 128 * 1024 * 2;
    P.d2Wb   = (unsigned short*)p;         p += 64 * 128 * 2;
    P.d3Wb   = (unsigned short*)p;         p += 128 * 64 * 2;

    hipLaunchKernelGGL(init_kernel, dim3(1), dim3(256), 0, stream, P.bar, P.loss);
    hipLaunchKernelGGL(persist, dim3(NBLK), dim3(256), 0, stream, P);
}

// Round 7
// 2463.010 us; speedup vs baseline: 7.7346x; 1.4718x over previous
//
#include <hip/hip_runtime.h>
#include <math.h>

#define NN_ 128   // batch
#define TT  100   // time steps
#define SS  128   // state dim
#define AA  32    // action dim
#define LL  1024  // hidden (= Z)
#define NBLK 264  // 256 matmul tiles + 8 head blocks
#define HRS  1032 // LDS h-stage row stride (bf16 elems): 2-way bank aliasing only (free)

typedef __attribute__((ext_vector_type(8))) short bf16x8;   // 8 bf16 in 4 VGPRs
typedef __attribute__((ext_vector_type(4))) float f32x4;

__device__ __forceinline__ float sigmoidf_(float x) { return 1.0f / (1.0f + expf(-x)); }
__device__ __forceinline__ unsigned short f2bf(float x) {
    union { float f; unsigned u; } v; v.f = x;
    return (unsigned short)((v.u + 0x7fffu + ((v.u >> 16) & 1u)) >> 16);   // RNE
}

// ---- agent-scope (LLC-coherent, L2-bypassing) access helpers
__device__ __forceinline__ bf16x8 lda16(const unsigned short* p) {   // 16B via 2x8B agent loads
    union { bf16x8 v; unsigned long long q[2]; } u;
    u.q[0] = __hip_atomic_load((const unsigned long long*)p,     __ATOMIC_RELAXED, __HIP_MEMORY_SCOPE_AGENT);
    u.q[1] = __hip_atomic_load((const unsigned long long*)p + 1, __ATOMIC_RELAXED, __HIP_MEMORY_SCOPE_AGENT);
    return u.v;
}
__device__ __forceinline__ void sta2(unsigned short* p, unsigned short v) {
    __hip_atomic_store(p, v, __ATOMIC_RELAXED, __HIP_MEMORY_SCOPE_AGENT);
}

struct PParams {
    const float *s, *a, *s_next, *eps;
    const float *eWih, *eWhh, *ebih, *ebhh;
    const float *muW, *mub, *lvW, *lvb;
    const float *dWih, *dWhh, *dbih, *dbhh;
    const float *d1W, *d1b, *d2W, *d2b, *d3W, *d3b;
    int *bar;
    int *endv, *startv, *limitv;
    unsigned short *hencAb, *hencBb, *hdecAb, *hdecBb, *hf_bf;
    unsigned short *eWih_b, *eWhh_b, *dWih_b, *dWhh_b, *mlW_b, *xenc_b, *adec_b;
    unsigned short *d1Wb, *d2Wb, *d3Wb;
    float *loss;
};

// ---------------------------------------------------------------- cooperative LLC->LDS h-tile stage
// 16 rows x 1024 cols bf16 (32 KB), 2048 16B chunks over 256 threads = 8 independent loads each.
__device__ __forceinline__ void stage_h(const unsigned short* __restrict__ src, int nb,
                                        unsigned short (&hstage)[16 * HRS], int tid) {
    bf16x8 v[8];
    #pragma unroll
    for (int k = 0; k < 8; ++k) {
        const int ci = tid + (k << 8);
        v[k] = lda16(src + (size_t)(nb + (ci >> 7)) * LL + (ci & 127) * 8);
    }
    #pragma unroll
    for (int k = 0; k < 8; ++k) {
        const int ci = tid + (k << 8);
        *(bf16x8*)&hstage[(ci >> 7) * HRS + (ci & 127) * 8] = v[k];
    }
}

// ---------------------------------------------------------------- grid barriers
// bar ints: [g*16] 8 group counters; [128] master; [132] broken; [144+g*16] 8 group flags.
// Monotone counters; gen starts at 1. Steady-state h flows via sc1/LLC -> no cache flushes needed.
__device__ void gbar_lite(int* bar, int bid, int tid, int gen) {
    __syncthreads();
    if (tid == 0) {
        __builtin_amdgcn_s_waitcnt(0);   // all prior (sc1) stores ACKed at LLC
        if (__hip_atomic_load(bar + 132, __ATOMIC_RELAXED, __HIP_MEMORY_SCOPE_AGENT) == 0) {
            const int g = bid & 7;
            int pos = __hip_atomic_fetch_add(bar + g * 16, 1, __ATOMIC_RELAXED, __HIP_MEMORY_SCOPE_AGENT);
            if (pos + 1 == (NBLK / 8) * gen) {
                int mp = __hip_atomic_fetch_add(bar + 128, 1, __ATOMIC_RELAXED, __HIP_MEMORY_SCOPE_AGENT);
                if (mp + 1 == 8 * gen) {
                    for (int b = 0; b < 8; ++b)
                        __hip_atomic_store(bar + 144 + b * 16, gen, __ATOMIC_RELAXED, __HIP_MEMORY_SCOPE_AGENT);
                }
            }
            int it = 0;
            while (__hip_atomic_load(bar + 144 + g * 16, __ATOMIC_RELAXED, __HIP_MEMORY_SCOPE_AGENT) < gen) {
                __builtin_amdgcn_s_sleep(1);
                if (++it > 4000000) {   // safety valve
                    __hip_atomic_store(bar + 132, 1, __ATOMIC_RELAXED, __HIP_MEMORY_SCOPE_AGENT);
                    break;
                }
            }
        }
    }
    __syncthreads();
}
// Heavy barrier (one-time, after phase-0 plain-store cast): full L2 writeback + invalidate.
__device__ void gbar_heavy(int* bar, int bid, int tid, int gen) {
    __syncthreads();
    if (tid == 0) __threadfence();      // wbl2: flush cast weights toward LLC
    gbar_lite(bar, bid, tid, gen);
    if (tid == 0) __threadfence();      // inv: drop stale lines
    __syncthreads();
}

// ---------------------------------------------------------------- init (separate launch)
__global__ void init_kernel(int* bar, float* loss) {
    for (int i = threadIdx.x; i < 5120; i += 256) bar[i] = 0;
    if (threadIdx.x == 0) loss[0] = 0.0f;
}

// ---------------------------------------------------------------- GRU step matmul tile
// 256 tiles: 8 n-blocks x 32 j-blocks(32 wide); 4 waves = 2 j-tiles x 2 K-halves.
// fp32 h state lives in `hold` registers of the kh==0 waves; bf16 h staged LLC->LDS per step.
template<int XK, bool IS_DEC>
__device__ void gru_tile(const int bid, const int tid,
    const unsigned short* __restrict__ h_bf, unsigned short* __restrict__ ho_bf,
    const unsigned short* __restrict__ Whh_b, const unsigned short* __restrict__ Wih_b,
    const unsigned short* __restrict__ x_bf,
    const float* __restrict__ bih, const float* __restrict__ bhh,
    const int* __restrict__ endv, unsigned short* __restrict__ hf_bf,
    int t, f32x4 (&red)[2][4][64], unsigned short (&hstage)[16 * HRS], f32x4& hold)
{
    const int lane = tid & 63, w = tid >> 6;
    const int jt = w & 1, kh = w >> 1;
    const int m = lane & 15, quad = lane >> 4;
    const int nb = (bid >> 5) << 4;            // 0..112 step 16
    const int jb = (bid & 31) * 32 + jt * 16;  // 0..1008 step 16
    const int jcol = jb + m;

    stage_h(h_bf, nb, hstage, tid);
    __syncthreads();

    f32x4 accr{}, accz{}, acchn{}, accxn{};

    {   // hidden: K = 1024, 32 chunks, split 16/16 across kh; A-fragments from LDS
        const int abase = m * HRS + quad * 8;
        const unsigned short* brp = Whh_b + (size_t)(0 * LL + jcol) * LL + quad * 8;
        const unsigned short* bzp = Whh_b + (size_t)(1 * LL + jcol) * LL + quad * 8;
        const unsigned short* bnp = Whh_b + (size_t)(2 * LL + jcol) * LL + quad * 8;
        #pragma unroll 4
        for (int c = kh * 16; c < kh * 16 + 16; ++c) {
            const int k0 = c * 32;
            bf16x8 av = *(const bf16x8*)&hstage[abase + k0];
            bf16x8 br = *(const bf16x8*)(brp + k0);
            bf16x8 bz = *(const bf16x8*)(bzp + k0);
            bf16x8 bn = *(const bf16x8*)(bnp + k0);
            accr  = __builtin_amdgcn_mfma_f32_16x16x32_bf16(av, br, accr, 0, 0, 0);
            accz  = __builtin_amdgcn_mfma_f32_16x16x32_bf16(av, bz, accz, 0, 0, 0);
            acchn = __builtin_amdgcn_mfma_f32_16x16x32_bf16(av, bn, acchn, 0, 0, 0);
        }
    }
    {   // input: K = XK (enc 160, dec 32); read-only -> plain L2-cached loads
        const int XC = XK / 32, XC0 = (XC + 1) / 2;
        const size_t xstride = IS_DEC ? (size_t)(50 * AA) : (size_t)(TT * (SS + AA));
        const unsigned short* xp  = x_bf + (size_t)(nb + m) * xstride + (size_t)t * XK + quad * 8;
        const unsigned short* brp = Wih_b + (size_t)(0 * LL + jcol) * XK + quad * 8;
        const unsigned short* bzp = Wih_b + (size_t)(1 * LL + jcol) * XK + quad * 8;
        const unsigned short* bnp = Wih_b + (size_t)(2 * LL + jcol) * XK + quad * 8;
        #pragma unroll
        for (int c = (kh ? XC0 : 0); c < (kh ? XC : XC0); ++c) {
            const int k0 = c * 32;
            bf16x8 av = *(const bf16x8*)(xp + k0);
            bf16x8 br = *(const bf16x8*)(brp + k0);
            bf16x8 bz = *(const bf16x8*)(bzp + k0);
            bf16x8 bn = *(const bf16x8*)(bnp + k0);
            accr  = __builtin_amdgcn_mfma_f32_16x16x32_bf16(av, br, accr, 0, 0, 0);
            accz  = __builtin_amdgcn_mfma_f32_16x16x32_bf16(av, bz, accz, 0, 0, 0);
            accxn = __builtin_amdgcn_mfma_f32_16x16x32_bf16(av, bn, accxn, 0, 0, 0);
        }
    }
    if (kh == 1) {
        red[jt][0][lane] = accr;  red[jt][1][lane] = accz;
        red[jt][2][lane] = acchn; red[jt][3][lane] = accxn;
    }
    __syncthreads();
    if (kh == 0) {
        accr  += red[jt][0][lane];  accz  += red[jt][1][lane];
        acchn += red[jt][2][lane];  accxn += red[jt][3][lane];
        const float br_  = bih[jcol] + bhh[jcol];
        const float bz_  = bih[LL + jcol] + bhh[LL + jcol];
        const float bxn_ = bih[2 * LL + jcol];
        const float bhn_ = bhh[2 * LL + jcol];
        #pragma unroll
        for (int i = 0; i < 4; ++i) {
            const int n = nb + quad * 4 + i;     // C layout: row = quad*4+reg, col = lane&15
            float r = sigmoidf_(accr[i] + br_);
            float z = sigmoidf_(accz[i] + bz_);
            float g = tanhf(accxn[i] + bxn_ + r * (acchn[i] + bhn_));
            float hn = (1.0f - z) * g + z * hold[i];
            hold[i] = hn;
            sta2(ho_bf + (size_t)n * LL + jcol, f2bf(hn));
            if (!IS_DEC) { if (endv[n] == t) sta2(hf_bf + (size_t)n * LL + jcol, f2bf(hn)); }
        }
    }
}

// ---------------------------------------------------------------- reparametrize tile -> hold regs + bf16
__device__ void emb_tile(const PParams& P, const int bid, const int tid,
                         f32x4 (&red)[2][4][64], unsigned short (&hstage)[16 * HRS], f32x4& hold)
{
    const int lane = tid & 63, w = tid >> 6;
    const int jt = w & 1, kh = w >> 1;
    const int m = lane & 15, quad = lane >> 4;
    const int nb = (bid >> 5) << 4;
    const int jb = (bid & 31) * 32 + jt * 16;
    const int jcol = jb + m;

    stage_h(P.hf_bf, nb, hstage, tid);
    __syncthreads();

    f32x4 accm{}, accl{};
    const int abase = m * HRS + quad * 8;
    const unsigned short* bmp = P.mlW_b + (size_t)jcol * LL + quad * 8;
    const unsigned short* blp = P.mlW_b + (size_t)(LL + jcol) * LL + quad * 8;
    #pragma unroll 4
    for (int c = kh * 16; c < kh * 16 + 16; ++c) {
        const int k0 = c * 32;
        bf16x8 av = *(const bf16x8*)&hstage[abase + k0];
        bf16x8 bm = *(const bf16x8*)(bmp + k0);
        bf16x8 bl = *(const bf16x8*)(blp + k0);
        accm = __builtin_amdgcn_mfma_f32_16x16x32_bf16(av, bm, accm, 0, 0, 0);
        accl = __builtin_amdgcn_mfma_f32_16x16x32_bf16(av, bl, accl, 0, 0, 0);
    }
    if (kh == 1) { red[jt][0][lane] = accm; red[jt][1][lane] = accl; }
    __syncthreads();
    if (kh == 0) {
        accm += red[jt][0][lane]; accl += red[jt][1][lane];
        #pragma unroll
        for (int i = 0; i < 4; ++i) {
            const int n = nb + quad * 4 + i;
            float mu = accm[i] + P.mub[jcol];
            float lv = accl[i] + P.lvb[jcol];
            float e = mu + expf(0.5f * lv) * P.eps[(size_t)n * LL + jcol];
            hold[i] = e;
            sta2(P.hdecAb + (size_t)n * LL + jcol, f2bf(e));
        }
    }
}

// ---------------------------------------------------------------- MFMA decoder head: 16 samples/block
__device__ void head_tile(const PParams& P, const int hb, const int tid,
                          const unsigned short* __restrict__ h_bf, int ti,
                          unsigned short (&hstage)[16 * HRS],
                          unsigned short (&ylds)[16][136], unsigned short (&y2lds)[16][72],
                          float (&lred)[4])
{
    const int lane = tid & 63, w = tid >> 6;
    const int m16 = lane & 15, quad = lane >> 4;
    const int n0 = hb * 16;

    stage_h(h_bf, n0, hstage, tid);
    __syncthreads();

    // ---- y1: K=1024, 8 j-tiles, wave w -> tiles {2w, 2w+1}; A from LDS
    #pragma unroll
    for (int jt = 0; jt < 2; ++jt) {
        const int c0 = (w * 2 + jt) * 16;
        f32x4 acc{};
        const int abase = m16 * HRS + quad * 8;
        const unsigned short* bp = P.d1Wb + (size_t)(c0 + m16) * LL + quad * 8;
        #pragma unroll 4
        for (int c = 0; c < 32; ++c) {
            bf16x8 av = *(const bf16x8*)&hstage[abase + c * 32];
            bf16x8 bv = *(const bf16x8*)(bp + c * 32);
            acc = __builtin_amdgcn_mfma_f32_16x16x32_bf16(av, bv, acc, 0, 0, 0);
        }
        const float b = P.d1b[c0 + m16];
        #pragma unroll
        for (int i = 0; i < 4; ++i)
            ylds[quad * 4 + i][c0 + m16] = f2bf(fmaxf(acc[i] + b, 0.0f));
    }
    __syncthreads();

    // ---- y2: K=128, 4 j-tiles, wave w -> tile w
    {
        const int c0 = w * 16;
        f32x4 acc{};
        #pragma unroll
        for (int c = 0; c < 4; ++c) {
            bf16x8 av = *(const bf16x8*)&ylds[m16][c * 32 + quad * 8];
            bf16x8 bv = *(const bf16x8*)(P.d2Wb + (size_t)(c0 + m16) * 128 + c * 32 + quad * 8);
            acc = __builtin_amdgcn_mfma_f32_16x16x32_bf16(av, bv, acc, 0, 0, 0);
        }
        const float b = P.d2b[c0 + m16];
        #pragma unroll
        for (int i = 0; i < 4; ++i)
            y2lds[quad * 4 + i][c0 + m16] = f2bf(fmaxf(acc[i] + b, 0.0f));
    }
    __syncthreads();

    // ---- y3: K=64, 8 j-tiles; fused masked L1
    float lsum = 0.0f;
    #pragma unroll
    for (int jt = 0; jt < 2; ++jt) {
        const int c0 = (w * 2 + jt) * 16;
        f32x4 acc{};
        #pragma unroll
        for (int c = 0; c < 2; ++c) {
            bf16x8 av = *(const bf16x8*)&y2lds[m16][c * 32 + quad * 8];
            bf16x8 bv = *(const bf16x8*)(P.d3Wb + (size_t)(c0 + m16) * 64 + c * 32 + quad * 8);
            acc = __builtin_amdgcn_mfma_f32_16x16x32_bf16(av, bv, acc, 0, 0, 0);
        }
        const int col = c0 + m16;
        const float b = P.d3b[col];
        #pragma unroll
        for (int i = 0; i < 4; ++i) {
            const int n = n0 + quad * 4 + i;
            if (ti < P.limitv[n]) {
                int tr = ti + P.startv[n]; if (tr >= TT) tr -= TT;
                float v = P.s_next[(size_t)n * TT * SS + (size_t)tr * SS + col];
                lsum += fabsf(v - (acc[i] + b));
            }
        }
    }
    for (int off = 32; off >= 1; off >>= 1) lsum += __shfl_down(lsum, off);
    if (lane == 0) lred[w] = lsum;
    __syncthreads();
    if (tid == 0) atomicAdd(P.loss, lred[0] + lred[1] + lred[2] + lred[3]);
}

// ---------------------------------------------------------------- the persistent kernel
__global__ __launch_bounds__(256, 2)
void persist(PParams P)
{
    __shared__ f32x4 red[2][4][64];                        // 8 KB matmul split-K
    __shared__ __align__(16) unsigned short hstage[16 * HRS];   // 33 KB h tile stage
    __shared__ __align__(16) unsigned short ylds[16][136];
    __shared__ __align__(16) unsigned short y2lds[16][72];
    __shared__ float lred[4];
    __shared__ int mint;
    __shared__ int wml[4], wme[4];
    const int bid = blockIdx.x, tid = threadIdx.x;
    int gen = 0;

    // ================= phase 0: cast (plain stores), split detection, h0, adec
    {
        const long N0 = 3072L * 160, N1 = N0 + 3072L * 1024, N2 = N1 + 3072L * 32,
                   N3 = N2 + 3072L * 1024, N4 = N3 + 1048576L, N5 = N4 + 1048576L,
                   N6 = N5 + 128L * 100 * 160, N7 = N6 + 131072L, N8 = N7 + 8192L,
                   N9 = N8 + 8192L;
        for (long i = (long)bid * 256 + tid; i < N9; i += (long)NBLK * 256) {
            if (i < N0)      P.eWih_b[i]      = f2bf(P.eWih[i]);
            else if (i < N1) P.eWhh_b[i - N0] = f2bf(P.eWhh[i - N0]);
            else if (i < N2) P.dWih_b[i - N1] = f2bf(P.dWih[i - N1]);
            else if (i < N3) P.dWhh_b[i - N2] = f2bf(P.dWhh[i - N2]);
            else if (i < N4) P.mlW_b[i - N3]  = f2bf(P.muW[i - N3]);
            else if (i < N5) P.mlW_b[1048576L + (i - N4)] = f2bf(P.lvW[i - N4]);
            else if (i < N6) {
                long j = i - N5;                  // n*16000 + t*160 + k
                int  k = (int)(j % 160);
                long nt = j / 160;
                int  t = (int)(nt % 100), n = (int)(nt / 100);
                float v = (k < SS) ? P.s[(size_t)n * TT * SS + (size_t)t * SS + k]
                                   : P.a[(size_t)n * TT * AA + (size_t)t * AA + (k - SS)];
                P.xenc_b[j] = f2bf(v);
            }
            else if (i < N7) P.d1Wb[i - N6] = f2bf(P.d1W[i - N6]);
            else if (i < N8) P.d2Wb[i - N7] = f2bf(P.d2W[i - N7]);
            else             P.d3Wb[i - N8] = f2bf(P.d3W[i - N8]);
        }
    }
    if (bid < NN_) {
        const int n = bid;
        if (tid == 0) mint = TT - 1;
        __syncthreads();
        int t = tid + 1;
        if (t < TT && tid < 128) {
            const float* row = P.s + (size_t)n * TT * SS + (size_t)t * SS;
            bool allz = true;
            for (int i = 0; i < SS; ++i) { if (row[i] != 0.0f) { allz = false; break; } }
            if (allz) atomicMin(&mint, t);
        }
        __syncthreads();
        const int m = mint, st = m + 1;
        if (tid == 0) { P.endv[n] = m - 1; P.startv[n] = st; P.limitv[n] = TT - 1 - m; }
        for (int idx = tid; idx < LL; idx += 256)
            P.hencAb[(size_t)n * LL + idx] = 0x3F80;   // bf16 1.0
        for (int idx = tid; idx < 50 * AA; idx += 256) {
            int i = idx >> 5, k = idx & 31;
            int tr = i + st; if (tr >= TT) tr -= TT;
            P.adec_b[(size_t)n * (50 * AA) + idx] =
                f2bf(P.a[(size_t)n * TT * AA + (size_t)tr * AA + k]);
        }
    }
    gbar_heavy(P.bar, bid, tid, ++gen);

    // ================= phase 0.5: all blocks compute ME = max(end), ML = max(limit)
    int ME, ML;
    {
        int lv = 0, ev = 0;
        if (tid < NN_) { lv = P.limitv[tid]; ev = P.endv[tid]; }
        for (int off = 32; off >= 1; off >>= 1) {
            lv = max(lv, __shfl_down(lv, off));
            ev = max(ev, __shfl_down(ev, off));
        }
        if ((tid & 63) == 0) { wml[tid >> 6] = lv; wme[tid >> 6] = ev; }
        __syncthreads();
        ML = max(max(wml[0], wml[1]), max(wml[2], wml[3]));
        ME = max(max(wme[0], wme[1]), max(wme[2], wme[3]));
        __syncthreads();
    }

    f32x4 hold = { 1.0f, 1.0f, 1.0f, 1.0f };   // enc h0 = ones (fp32 state lives here)

    // ================= encoder: t = 0..ME (<= 97)
    for (int t = 0; t <= ME; ++t) {
        if (bid < 256) {
            const unsigned short* hib = (t & 1) ? P.hencBb : P.hencAb;
            unsigned short*       hob = (t & 1) ? P.hencAb : P.hencBb;
            gru_tile<160, false>(bid, tid, hib, hob,
                                 P.eWhh_b, P.eWih_b, P.xenc_b, P.ebih, P.ebhh,
                                 P.endv, P.hf_bf, t, red, hstage, hold);
        }
        gbar_lite(P.bar, bid, tid, ++gen);
    }

    // ================= reparametrize (deposits decoder h0 into hold regs)
    if (bid < 256) emb_tile(P, bid, tid, red, hstage, hold);
    gbar_lite(P.bar, bid, tid, ++gen);

    // ================= decoder: i = 0..ML; matmul (i<ML) overlaps head for step i-1
    for (int i = 0; i <= ML; ++i) {
        const unsigned short* hib = (i & 1) ? P.hdecBb : P.hdecAb;
        if (bid < 256) {
            if (i < ML) {
                unsigned short* hob = (i & 1) ? P.hdecAb : P.hdecBb;
                gru_tile<32, true>(bid, tid, hib, hob,
                                   P.dWhh_b, P.dWih_b, P.adec_b, P.dbih, P.dbhh,
                                   nullptr, nullptr, i, red, hstage, hold);
            }
        } else if (i >= 1) {
            head_tile(P, bid - 256, tid, hib, i - 1, hstage, ylds, y2lds, lred);
        }
        gbar_lite(P.bar, bid, tid, ++gen);
    }
}

// ---------------------------------------------------------------- launch
extern "C" void kernel_launch(void* const* d_in, const int* in_sizes, int n_in,
                              void* d_out, int out_size, void* d_ws, size_t ws_size,
                              hipStream_t stream) {
    PParams P;
    P.s      = (const float*)d_in[0];
    P.a      = (const float*)d_in[1];
    P.s_next = (const float*)d_in[3];
    P.eps    = (const float*)d_in[4];
    P.eWih   = (const float*)d_in[5];
    P.eWhh   = (const float*)d_in[6];
    P.ebih   = (const float*)d_in[7];
    P.ebhh   = (const float*)d_in[8];
    P.muW    = (const float*)d_in[9];
    P.mub    = (const float*)d_in[10];
    P.lvW    = (const float*)d_in[11];
    P.lvb    = (const float*)d_in[12];
    // st1..st3 (13..18) dead code w.r.t. the loss
    P.dWih   = (const float*)d_in[19];
    P.dWhh   = (const float*)d_in[20];
    P.dbih   = (const float*)d_in[21];
    P.dbhh   = (const float*)d_in[22];
    P.d1W    = (const float*)d_in[23];
    P.d1b    = (const float*)d_in[24];
    P.d2W    = (const float*)d_in[25];
    P.d2b    = (const float*)d_in[26];
    P.d3W    = (const float*)d_in[27];
    P.d3b    = (const float*)d_in[28];
    P.loss   = (float*)d_out;

    char* p = (char*)d_ws;
    P.bar    = (int*)p;                    p += 20480;
    P.endv   = (int*)p;                    p += 512;
    P.startv = (int*)p;                    p += 512;
    P.limitv = (int*)p;                    p += 512;
    p += 2560;                             // pad
    P.hencAb = (unsigned short*)p;         p += 128 * 1024 * 2;
    P.hencBb = (unsigned short*)p;         p += 128 * 1024 * 2;
    P.hdecAb = (unsigned short*)p;         p += 128 * 1024 * 2;
    P.hdecBb = (unsigned short*)p;         p += 128 * 1024 * 2;
    P.hf_bf  = (unsigned short*)p;         p += 128 * 1024 * 2;
    P.eWih_b = (unsigned short*)p;         p += 3072 * 160 * 2;
    P.eWhh_b = (unsigned short*)p;         p += 3072 * 1024 * 2;
    P.dWih_b = (unsigned short*)p;         p += 3072 * 32 * 2;
    P.dWhh_b = (unsigned short*)p;         p += 3072 * 1024 * 2;
    P.mlW_b  = (unsigned short*)p;         p += 2048 * 1024 * 2;
    P.xenc_b = (unsigned short*)p;         p += 128 * 100 * 160 * 2;
    P.adec_b = (unsigned short*)p;         p += 128 * 50 * 32 * 2;
    P.d1Wb   = (unsigned short*)p;         p += 128 * 1024 * 2;
    P.d2Wb   = (unsigned short*)p;         p += 64 * 128 * 2;
    P.d3Wb   = (unsigned short*)p;         p += 128 * 64 * 2;

    hipLaunchKernelGGL(init_kernel, dim3(1), dim3(256), 0, stream, P.bar, P.loss);
    hipLaunchKernelGGL(persist, dim3(NBLK), dim3(256), 0, stream, P);
}